// Round 1
// baseline (1461.165 us; speedup 1.0000x reference)
//
#include <hip/hip_runtime.h>
#include <cstdint>
#include <cstddef>

// ---------------- problem constants ----------------
constexpr int B_   = 16;
constexpr int L_   = 1024;
constexpr int E_   = 192;
constexpr int DM   = 196;   // D_MODEL
constexpr int DI   = 392;   // D_INNER
constexpr int DS   = 16;    // D_STATE
constexpr int DTR  = 13;    // DT_RANK
constexpr int NTOK = B_ * L_;            // 16384
constexpr int XDW  = DTR + 2 * DS;       // 45

constexpr size_t HW_SZ = (size_t)NTOK * DM;   // 3,211,264
constexpr size_t DI_SZ = (size_t)NTOK * DI;   // 6,422,528
constexpr size_t XD_SZ = (size_t)NTOK * XDW;  //   737,280

// ---------------- workspace layout (float offsets) ----------------
// xi_f/xi_b regions are reused: xi -> delta -> fo/bo
// ys_f/ys_b regions host early temps: Xp (patch gather) / tok_raw
constexpr size_t O_H    = 0;
constexpr size_t O_XI_F = O_H    + HW_SZ;
constexpr size_t O_XI_B = O_XI_F + DI_SZ;
constexpr size_t O_Z_F  = O_XI_B + DI_SZ;
constexpr size_t O_Z_B  = O_Z_F  + DI_SZ;
constexpr size_t O_XC_F = O_Z_B  + DI_SZ;
constexpr size_t O_XC_B = O_XC_F + DI_SZ;
constexpr size_t O_XD_F = O_XC_B + DI_SZ;
constexpr size_t O_XD_B = O_XD_F + XD_SZ;
constexpr size_t O_YS_F = O_XD_B + XD_SZ;
constexpr size_t O_YS_B = O_YS_F + DI_SZ;
// total floats = O_YS_B + DI_SZ = 56,066,048  (~214 MiB)

// ---------------- helpers ----------------
__device__ __forceinline__ float siluf(float x) {
    return x / (1.f + __expf(-x));
}

// block of 256 threads (4 waves of 64)
__device__ __forceinline__ float blk_sum(float v, float* red) {
    #pragma unroll
    for (int o = 32; o > 0; o >>= 1) v += __shfl_down(v, o);
    int w = threadIdx.x >> 6;
    __syncthreads();
    if ((threadIdx.x & 63) == 0) red[w] = v;
    __syncthreads();
    return red[0] + red[1] + red[2] + red[3];
}

// ---------------- K0: gather patches into (NTOK, 192) ----------------
__global__ __launch_bounds__(256) void gather_patch(const float* __restrict__ x,
                                                    float* __restrict__ Xp) {
    int i = blockIdx.x * 256 + threadIdx.x;      // < NTOK*192
    int tok = i / 192, r = i - tok * 192;
    int c = r >> 6, pq = r & 63, p = pq >> 3, q = pq & 7;
    int b = tok >> 10, l = tok & 1023, hh = l >> 5, wv = l & 31;
    Xp[i] = x[(((size_t)(b * 3 + c) * 256 + hh * 8 + p) << 8) + wv * 8 + q];
}

// ---------------- generic fp32 GEMM: C(M,N) = A(M,K) @ W(N,K)^T (+bias) ----------------
// A row stride == K. Optional flip of A rows within each batch of 1024 rows.
__global__ __launch_bounds__(256) void gemm_xt(const float* __restrict__ A,
                                               const float* __restrict__ W,
                                               const float* __restrict__ bias,
                                               float* __restrict__ C,
                                               int M, int N, int K, int ldc, int flip) {
    __shared__ __align__(16) float As[16][68];
    __shared__ __align__(16) float Ws[16][68];
    const int m0 = blockIdx.x * 64, n0 = blockIdx.y * 64;
    const int t = threadIdx.x;
    const int tx = t & 15, ty = t >> 4;
    float acc[4][4] = {};
    const int KT = (K + 15) >> 4;

    const int arow_l = t >> 2;          // 0..63
    const int kq = (t & 3) * 4;         // 0,4,8,12

    for (int kt = 0; kt < KT; ++kt) {
        const int k0 = kt << 4;
        // load A tile (64 x 16) -> As[k][m]
        {
            int ar = m0 + arow_l;
            int am = flip ? ((ar & ~1023) + 1023 - (ar & 1023)) : ar;
            const float* ap = A + (size_t)am * K;
            #pragma unroll
            for (int jj = 0; jj < 4; ++jj) {
                int kk = k0 + kq + jj;
                As[kq + jj][arow_l] = (kk < K) ? ap[kk] : 0.f;
            }
        }
        // load W tile (64 x 16) -> Ws[k][n]
        {
            int wr = n0 + arow_l;
            const float* wp = W + (size_t)wr * K;
            bool okn = (wr < N);
            #pragma unroll
            for (int jj = 0; jj < 4; ++jj) {
                int kk = k0 + kq + jj;
                Ws[kq + jj][arow_l] = (okn && kk < K) ? wp[kk] : 0.f;
            }
        }
        __syncthreads();
        #pragma unroll
        for (int k = 0; k < 16; ++k) {
            float av[4], wv[4];
            *reinterpret_cast<float4*>(av) = *reinterpret_cast<const float4*>(&As[k][ty * 4]);
            *reinterpret_cast<float4*>(wv) = *reinterpret_cast<const float4*>(&Ws[k][tx * 4]);
            #pragma unroll
            for (int i = 0; i < 4; ++i)
                #pragma unroll
                for (int j = 0; j < 4; ++j)
                    acc[i][j] = fmaf(av[i], wv[j], acc[i][j]);
        }
        __syncthreads();
    }
    #pragma unroll
    for (int i = 0; i < 4; ++i) {
        int m = m0 + ty * 4 + i;
        #pragma unroll
        for (int j = 0; j < 4; ++j) {
            int n = n0 + tx * 4 + j;
            if (n < N) {
                float v = acc[i][j];
                if (bias) v += bias[n];
                C[(size_t)m * ldc + n] = v;
            }
        }
    }
}

// ---------------- K1b: LN + SiLU + positional features -> h (NTOK, 196) ----------------
__global__ __launch_bounds__(256) void ln_silu_pos(const float* __restrict__ tok,
                                                   const float* __restrict__ g,
                                                   const float* __restrict__ bb,
                                                   float* __restrict__ h) {
    __shared__ float red[4];
    const int t = blockIdx.x;
    const int e = threadIdx.x;
    float v = (e < E_) ? tok[(size_t)t * E_ + e] : 0.f;
    float s1 = blk_sum(v, red);
    float s2 = blk_sum(v * v, red);
    float mean = s1 * (1.f / E_);
    float var = s2 * (1.f / E_) - mean * mean;
    float inv = rsqrtf(var + 1e-5f);
    if (e < E_) {
        float o = (v - mean) * inv * g[e] + bb[e];
        h[(size_t)t * DM + e] = siluf(o);
    } else if (e < DM) {
        const int l = t & 1023;
        const float scale = 0.19634954084936207f;  // 2*pi/32
        float pv;
        if (e == E_)          pv = sinf(l * scale);
        else if (e == E_ + 1) pv = cosf(l * scale);
        else if (e == E_ + 2) pv = sinf((float)(l >> 5) * scale);
        else                  pv = cosf((float)(l >> 5) * scale);
        h[(size_t)t * DM + e] = pv;
    }
}

// ---------------- K3: depthwise causal conv(4) + SiLU, both dirs ----------------
__global__ __launch_bounds__(256) void conv_silu_kernel(
        const float* __restrict__ xi_f, const float* __restrict__ xi_b,
        float* __restrict__ xc_f, float* __restrict__ xc_b,
        const float* __restrict__ fw, const float* __restrict__ fb2,
        const float* __restrict__ bw, const float* __restrict__ bb2) {
    int i = blockIdx.x * 256 + threadIdx.x;        // < 2*DI_SZ
    int dir = i >= (int)DI_SZ;
    int j = dir ? i - (int)DI_SZ : i;
    int tok = j / DI;
    int d = j - tok * DI;
    int l = tok & 1023;
    const float* xi = dir ? xi_b : xi_f;
    const float* w = (dir ? bw : fw) + d * 4;
    float acc = (dir ? bb2 : fb2)[d];
    #pragma unroll
    for (int k = 0; k < 4; ++k) {
        int ll = l + k - 3;
        if (ll >= 0) acc = fmaf(xi[(size_t)j + (k - 3) * DI], w[k], acc);
    }
    (dir ? xc_b : xc_f)[j] = siluf(acc);
}

// ---------------- K4: delta = softplus(dt @ dt_w^T + dt_b), both dirs ----------------
__global__ __launch_bounds__(256) void delta_kernel(
        const float* __restrict__ xd_f, const float* __restrict__ xd_b,
        float* __restrict__ dl_f, float* __restrict__ dl_b,
        const float* __restrict__ f_dt_w, const float* __restrict__ f_dt_b,
        const float* __restrict__ b_dt_w, const float* __restrict__ b_dt_b) {
    int i = blockIdx.x * 256 + threadIdx.x;
    int dir = i >= (int)DI_SZ;
    int j = dir ? i - (int)DI_SZ : i;
    int tok = j / DI;
    int d = j - tok * DI;
    const float* xd = (dir ? xd_b : xd_f) + (size_t)tok * XDW;
    const float* w = (dir ? b_dt_w : f_dt_w) + d * DTR;
    float acc = (dir ? b_dt_b : f_dt_b)[d];
    #pragma unroll
    for (int r = 0; r < DTR; ++r) acc = fmaf(xd[r], w[r], acc);
    float sp = fmaxf(acc, 0.f) + log1pf(__expf(-fabsf(acc)));
    (dir ? dl_b : dl_f)[j] = sp;
}

// ---------------- K5: selective scan, lane per (dir,b,d,n) ----------------
__global__ __launch_bounds__(256) void scan_kernel(
        const float* __restrict__ dlt_f, const float* __restrict__ dlt_b,
        const float* __restrict__ xc_f, const float* __restrict__ xc_b,
        const float* __restrict__ xd_f, const float* __restrict__ xd_b,
        float* __restrict__ ys_f, float* __restrict__ ys_b,
        const float* __restrict__ fA, const float* __restrict__ bA) {
    const int gc = blockIdx.x * 16 + (threadIdx.x >> 4);   // chain id, < 2*16*392
    const int n = threadIdx.x & 15;
    const int dir = gc >= (B_ * DI);
    const int r = dir ? gc - B_ * DI : gc;
    const int b = r / DI, d = r - (r / DI) * DI;
    const float* dp = (dir ? dlt_b : dlt_f) + (size_t)b * L_ * DI + d;
    const float* up = (dir ? xc_b : xc_f) + (size_t)b * L_ * DI + d;
    const float* bc = (dir ? xd_b : xd_f) + (size_t)b * L_ * XDW;
    float* yp = (dir ? ys_b : ys_f) + (size_t)b * L_ * DI + d;
    const float Av = -expf((dir ? bA : fA)[d * DS + n]);
    float h = 0.f;
    for (int t = 0; t < L_; ++t) {
        float dl = dp[(size_t)t * DI];
        float u  = up[(size_t)t * DI];
        float Bn = bc[t * XDW + DTR + n];
        float Cn = bc[t * XDW + DTR + DS + n];
        float dA = __expf(dl * Av);
        h = fmaf(dA, h, dl * Bn * u);
        float p = h * Cn;
        p += __shfl_xor(p, 1);
        p += __shfl_xor(p, 2);
        p += __shfl_xor(p, 4);
        p += __shfl_xor(p, 8);
        if (n == 0) yp[(size_t)t * DI] = p;
    }
}

// ---------------- K6: gate: ys = (ys + D*xc) * silu(z), in place, both dirs ----------------
__global__ __launch_bounds__(256) void gate_kernel(
        float* __restrict__ ys_f, float* __restrict__ ys_b,
        const float* __restrict__ xc_f, const float* __restrict__ xc_b,
        const float* __restrict__ z_f, const float* __restrict__ z_b,
        const float* __restrict__ fD, const float* __restrict__ bD) {
    int i = blockIdx.x * 256 + threadIdx.x;
    int dir = i >= (int)DI_SZ;
    int j = dir ? i - (int)DI_SZ : i;
    int tok = j / DI;
    int d = j - tok * DI;
    float* ys = dir ? ys_b : ys_f;
    float y = ys[j] + (dir ? bD : fD)[d] * (dir ? xc_b : xc_f)[j];
    float z = (dir ? z_b : z_f)[j];
    ys[j] = y * siluf(z);
}

// ---------------- K7b: init d_out to cls_b ----------------
__global__ void out_init(float* __restrict__ out, const float* __restrict__ cls_b) {
    if (threadIdx.x < B_) out[threadIdx.x] = cls_b[0];
}

// ---------------- K8: combine, LN, SiLU, residual, cls head ----------------
__global__ __launch_bounds__(256) void final_kernel(
        const float* __restrict__ fo, const float* __restrict__ bo,
        const float* __restrict__ h, const float* __restrict__ g,
        const float* __restrict__ bb, const float* __restrict__ cls_w,
        float* __restrict__ out) {
    __shared__ float red[4];
    const int t = blockIdx.x;
    const int b = t >> 10, l = t & 1023;
    const int e = threadIdx.x;
    float v = 0.f;
    if (e < DM)
        v = 0.5f * (fo[(size_t)t * DM + e] + bo[((size_t)b * L_ + (L_ - 1 - l)) * DM + e]);
    float s1 = blk_sum(v, red);
    float s2 = blk_sum(v * v, red);
    float mean = s1 * (1.f / DM);
    float var = s2 * (1.f / DM) - mean * mean;
    float inv = rsqrtf(var + 1e-5f);
    float c = 0.f;
    if (e < DM) {
        float o = (v - mean) * inv * g[e] + bb[e];
        o = siluf(o) + h[(size_t)t * DM + e];
        c = o * cls_w[e];
    }
    float s = blk_sum(c, red);
    if (e == 0) atomicAdd(&out[b], s * (1.f / 1024.f));
}

// ---------------- launch ----------------
extern "C" void kernel_launch(void* const* d_in, const int* in_sizes, int n_in,
                              void* d_out, int out_size, void* d_ws, size_t ws_size,
                              hipStream_t stream) {
    const float* x        = (const float*)d_in[0];
    const float* patch_w  = (const float*)d_in[1];
    const float* patch_b  = (const float*)d_in[2];
    const float* pe_g     = (const float*)d_in[3];
    const float* pe_b     = (const float*)d_in[4];
    const float* blk_g    = (const float*)d_in[5];
    const float* blk_b    = (const float*)d_in[6];
    const float* cls_w    = (const float*)d_in[7];
    const float* cls_b    = (const float*)d_in[8];
    const float* f_in_w   = (const float*)d_in[9];
    const float* f_conv_w = (const float*)d_in[10];
    const float* f_conv_b = (const float*)d_in[11];
    const float* f_xp_w   = (const float*)d_in[12];
    const float* f_dt_w   = (const float*)d_in[13];
    const float* f_dt_b   = (const float*)d_in[14];
    const float* f_A_log  = (const float*)d_in[15];
    const float* f_D      = (const float*)d_in[16];
    const float* f_out_w  = (const float*)d_in[17];
    const float* b_in_w   = (const float*)d_in[18];
    const float* b_conv_w = (const float*)d_in[19];
    const float* b_conv_b = (const float*)d_in[20];
    const float* b_xp_w   = (const float*)d_in[21];
    const float* b_dt_w   = (const float*)d_in[22];
    const float* b_dt_b   = (const float*)d_in[23];
    const float* b_A_log  = (const float*)d_in[24];
    const float* b_D      = (const float*)d_in[25];
    const float* b_out_w  = (const float*)d_in[26];

    float* ws = (float*)d_ws;
    float* out = (float*)d_out;

    float* Hb   = ws + O_H;
    float* XIf  = ws + O_XI_F;   // xi_f -> delta_f -> fo
    float* XIb  = ws + O_XI_B;   // xi_b -> delta_b -> bo
    float* Zf   = ws + O_Z_F;
    float* Zb   = ws + O_Z_B;
    float* XCf  = ws + O_XC_F;
    float* XCb  = ws + O_XC_B;
    float* XDf  = ws + O_XD_F;
    float* XDb  = ws + O_XD_B;
    float* YSf  = ws + O_YS_F;   // early: Xp temp
    float* YSb  = ws + O_YS_B;   // early: tok_raw temp

    // K0: gather patches
    gather_patch<<<(NTOK * 192) / 256, 256, 0, stream>>>(x, YSf);
    // K1: tok = Xp @ patch_w^T + patch_b
    gemm_xt<<<dim3(NTOK / 64, 3), 256, 0, stream>>>(YSf, patch_w, patch_b, YSb,
                                                    NTOK, E_, 192, E_, 0);
    // K1b: LN + SiLU + pos -> h
    ln_silu_pos<<<NTOK, 256, 0, stream>>>(YSb, pe_g, pe_b, Hb);
    // K2: xz GEMMs (xi and z halves, fwd and flipped-bwd)
    gemm_xt<<<dim3(NTOK / 64, 7), 256, 0, stream>>>(Hb, f_in_w, nullptr, XIf,
                                                    NTOK, DI, DM, DI, 0);
    gemm_xt<<<dim3(NTOK / 64, 7), 256, 0, stream>>>(Hb, f_in_w + (size_t)DI * DM, nullptr, Zf,
                                                    NTOK, DI, DM, DI, 0);
    gemm_xt<<<dim3(NTOK / 64, 7), 256, 0, stream>>>(Hb, b_in_w, nullptr, XIb,
                                                    NTOK, DI, DM, DI, 1);
    gemm_xt<<<dim3(NTOK / 64, 7), 256, 0, stream>>>(Hb, b_in_w + (size_t)DI * DM, nullptr, Zb,
                                                    NTOK, DI, DM, DI, 1);
    // K3: conv + silu
    conv_silu_kernel<<<(2 * (int)DI_SZ) / 256, 256, 0, stream>>>(
        XIf, XIb, XCf, XCb, f_conv_w, f_conv_b, b_conv_w, b_conv_b);
    // K2b: x_dbl GEMMs
    gemm_xt<<<dim3(NTOK / 64, 1), 256, 0, stream>>>(XCf, f_xp_w, nullptr, XDf,
                                                    NTOK, XDW, DI, XDW, 0);
    gemm_xt<<<dim3(NTOK / 64, 1), 256, 0, stream>>>(XCb, b_xp_w, nullptr, XDb,
                                                    NTOK, XDW, DI, XDW, 0);
    // K4: delta (writes over xi regions, which are dead now)
    delta_kernel<<<(2 * (int)DI_SZ) / 256, 256, 0, stream>>>(
        XDf, XDb, XIf, XIb, f_dt_w, f_dt_b, b_dt_w, b_dt_b);
    // K5: selective scan
    scan_kernel<<<(2 * B_ * DI) / 16, 256, 0, stream>>>(
        XIf, XIb, XCf, XCb, XDf, XDb, YSf, YSb, f_A_log, b_A_log);
    // K6: gating in place
    gate_kernel<<<(2 * (int)DI_SZ) / 256, 256, 0, stream>>>(
        YSf, YSb, XCf, XCb, Zf, Zb, f_D, b_D);
    // K7: out projections (write over delta regions -> fo/bo)
    gemm_xt<<<dim3(NTOK / 64, 4), 256, 0, stream>>>(YSf, f_out_w, nullptr, XIf,
                                                    NTOK, DM, DI, DM, 0);
    gemm_xt<<<dim3(NTOK / 64, 4), 256, 0, stream>>>(YSb, b_out_w, nullptr, XIb,
                                                    NTOK, DM, DI, DM, 0);
    // K7b + K8: init out, then accumulate head
    out_init<<<1, 64, 0, stream>>>(out, cls_b);
    final_kernel<<<NTOK, 256, 0, stream>>>(XIf, XIb, Hb, blk_g, blk_b, cls_w, out);
}

// Round 2
// 1417.188 us; speedup vs baseline: 1.0310x; 1.0310x over previous
//
#include <hip/hip_runtime.h>
#include <cstdint>
#include <cstddef>

// ---------------- problem constants ----------------
constexpr int B_   = 16;
constexpr int L_   = 1024;
constexpr int E_   = 192;
constexpr int DM   = 196;   // D_MODEL
constexpr int DI   = 392;   // D_INNER
constexpr int DS   = 16;    // D_STATE
constexpr int DTR  = 13;    // DT_RANK
constexpr int NTOK = B_ * L_;            // 16384
constexpr int XDW  = DTR + 2 * DS;       // 45
constexpr int CH   = B_ * DI;            // 6272 chains per direction

constexpr size_t HW_SZ = (size_t)NTOK * DM;   // 3,211,264
constexpr size_t DI_SZ = (size_t)NTOK * DI;   // 6,422,528
constexpr size_t XD_SZ = (size_t)NTOK * XDW;  //   737,280

// ---------------- workspace layout (float offsets) ----------------
// xi_f/xi_b regions are reused: xi -> deltaT -> fo/bo
// ys_f/ys_b regions host early temps: Xp (patch gather) / tok_raw
constexpr size_t O_H    = 0;
constexpr size_t O_XI_F = O_H    + HW_SZ;
constexpr size_t O_XI_B = O_XI_F + DI_SZ;
constexpr size_t O_Z_F  = O_XI_B + DI_SZ;
constexpr size_t O_Z_B  = O_Z_F  + DI_SZ;
constexpr size_t O_XC_F = O_Z_B  + DI_SZ;
constexpr size_t O_XC_B = O_XC_F + DI_SZ;
constexpr size_t O_XD_F = O_XC_B + DI_SZ;
constexpr size_t O_XD_B = O_XD_F + XD_SZ;
constexpr size_t O_YS_F = O_XD_B + XD_SZ;
constexpr size_t O_YS_B = O_YS_F + DI_SZ;
// total floats = O_YS_B + DI_SZ = 56,066,048  (~214 MiB)

// ---------------- helpers ----------------
__device__ __forceinline__ float siluf(float x) {
    return x / (1.f + __expf(-x));
}

// block of 256 threads (4 waves of 64)
__device__ __forceinline__ float blk_sum(float v, float* red) {
    #pragma unroll
    for (int o = 32; o > 0; o >>= 1) v += __shfl_down(v, o);
    int w = threadIdx.x >> 6;
    __syncthreads();
    if ((threadIdx.x & 63) == 0) red[w] = v;
    __syncthreads();
    return red[0] + red[1] + red[2] + red[3];
}

// ---------------- K0: gather patches into (NTOK, 192) ----------------
__global__ __launch_bounds__(256) void gather_patch(const float* __restrict__ x,
                                                    float* __restrict__ Xp) {
    int i = blockIdx.x * 256 + threadIdx.x;      // < NTOK*192
    int tok = i / 192, r = i - tok * 192;
    int c = r >> 6, pq = r & 63, p = pq >> 3, q = pq & 7;
    int b = tok >> 10, l = tok & 1023, hh = l >> 5, wv = l & 31;
    Xp[i] = x[(((size_t)(b * 3 + c) * 256 + hh * 8 + p) << 8) + wv * 8 + q];
}

// ---------------- generic fp32 GEMM: C(M,N) = A(M,K) @ W(N,K)^T (+bias) ----------------
__global__ __launch_bounds__(256) void gemm_xt(const float* __restrict__ A,
                                               const float* __restrict__ W,
                                               const float* __restrict__ bias,
                                               float* __restrict__ C,
                                               int M, int N, int K, int ldc, int flip) {
    __shared__ __align__(16) float As[16][68];
    __shared__ __align__(16) float Ws[16][68];
    const int m0 = blockIdx.x * 64, n0 = blockIdx.y * 64;
    const int t = threadIdx.x;
    const int tx = t & 15, ty = t >> 4;
    float acc[4][4] = {};
    const int KT = (K + 15) >> 4;

    const int arow_l = t >> 2;          // 0..63
    const int kq = (t & 3) * 4;         // 0,4,8,12

    for (int kt = 0; kt < KT; ++kt) {
        const int k0 = kt << 4;
        {
            int ar = m0 + arow_l;
            int am = flip ? ((ar & ~1023) + 1023 - (ar & 1023)) : ar;
            const float* ap = A + (size_t)am * K;
            #pragma unroll
            for (int jj = 0; jj < 4; ++jj) {
                int kk = k0 + kq + jj;
                As[kq + jj][arow_l] = (kk < K) ? ap[kk] : 0.f;
            }
        }
        {
            int wr = n0 + arow_l;
            const float* wp = W + (size_t)wr * K;
            bool okn = (wr < N);
            #pragma unroll
            for (int jj = 0; jj < 4; ++jj) {
                int kk = k0 + kq + jj;
                Ws[kq + jj][arow_l] = (okn && kk < K) ? wp[kk] : 0.f;
            }
        }
        __syncthreads();
        #pragma unroll
        for (int k = 0; k < 16; ++k) {
            float av[4], wv[4];
            *reinterpret_cast<float4*>(av) = *reinterpret_cast<const float4*>(&As[k][ty * 4]);
            *reinterpret_cast<float4*>(wv) = *reinterpret_cast<const float4*>(&Ws[k][tx * 4]);
            #pragma unroll
            for (int i = 0; i < 4; ++i)
                #pragma unroll
                for (int j = 0; j < 4; ++j)
                    acc[i][j] = fmaf(av[i], wv[j], acc[i][j]);
        }
        __syncthreads();
    }
    #pragma unroll
    for (int i = 0; i < 4; ++i) {
        int m = m0 + ty * 4 + i;
        #pragma unroll
        for (int j = 0; j < 4; ++j) {
            int n = n0 + tx * 4 + j;
            if (n < N) {
                float v = acc[i][j];
                if (bias) v += bias[n];
                C[(size_t)m * ldc + n] = v;
            }
        }
    }
}

// ---------------- K1b: LN + SiLU + positional features -> h (NTOK, 196) ----------------
__global__ __launch_bounds__(256) void ln_silu_pos(const float* __restrict__ tok,
                                                   const float* __restrict__ g,
                                                   const float* __restrict__ bb,
                                                   float* __restrict__ h) {
    __shared__ float red[4];
    const int t = blockIdx.x;
    const int e = threadIdx.x;
    float v = (e < E_) ? tok[(size_t)t * E_ + e] : 0.f;
    float s1 = blk_sum(v, red);
    float s2 = blk_sum(v * v, red);
    float mean = s1 * (1.f / E_);
    float var = s2 * (1.f / E_) - mean * mean;
    float inv = rsqrtf(var + 1e-5f);
    if (e < E_) {
        float o = (v - mean) * inv * g[e] + bb[e];
        h[(size_t)t * DM + e] = siluf(o);
    } else if (e < DM) {
        const int l = t & 1023;
        const float scale = 0.19634954084936207f;  // 2*pi/32
        float pv;
        if (e == E_)          pv = sinf(l * scale);
        else if (e == E_ + 1) pv = cosf(l * scale);
        else if (e == E_ + 2) pv = sinf((float)(l >> 5) * scale);
        else                  pv = cosf((float)(l >> 5) * scale);
        h[(size_t)t * DM + e] = pv;
    }
}

// ---------------- K3: depthwise causal conv(4) + SiLU, both dirs ----------------
__global__ __launch_bounds__(256) void conv_silu_kernel(
        const float* __restrict__ xi_f, const float* __restrict__ xi_b,
        float* __restrict__ xc_f, float* __restrict__ xc_b,
        const float* __restrict__ fw, const float* __restrict__ fb2,
        const float* __restrict__ bw, const float* __restrict__ bb2) {
    int i = blockIdx.x * 256 + threadIdx.x;        // < 2*DI_SZ
    int dir = i >= (int)DI_SZ;
    int j = dir ? i - (int)DI_SZ : i;
    int tok = j / DI;
    int d = j - tok * DI;
    int l = tok & 1023;
    const float* xi = dir ? xi_b : xi_f;
    const float* w = (dir ? bw : fw) + d * 4;
    float acc = (dir ? bb2 : fb2)[d];
    #pragma unroll
    for (int k = 0; k < 4; ++k) {
        int ll = l + k - 3;
        if (ll >= 0) acc = fmaf(xi[(size_t)j + (k - 3) * DI], w[k], acc);
    }
    (dir ? xc_b : xc_f)[j] = siluf(acc);
}

// ---------------- K4: delta = softplus(dt @ dt_w^T + dt_b), TRANSPOSED out ----------------
// thread i -> (dir, chain r, t); writes dlT[r*1024 + t] (chain-major, coalesced)
__global__ __launch_bounds__(256) void delta_kernel(
        const float* __restrict__ xd_f, const float* __restrict__ xd_b,
        float* __restrict__ dlT_f, float* __restrict__ dlT_b,
        const float* __restrict__ f_dt_w, const float* __restrict__ f_dt_b,
        const float* __restrict__ b_dt_w, const float* __restrict__ b_dt_b) {
    int i = blockIdx.x * 256 + threadIdx.x;       // < 2*DI_SZ
    int dir = i >= (int)DI_SZ;
    int j = dir ? i - (int)DI_SZ : i;             // r*1024 + t
    int r = j >> 10, t = j & 1023;
    int b = r / DI, d = r - (r / DI) * DI;
    size_t tok = ((size_t)b << 10) + t;
    const float* xd = (dir ? xd_b : xd_f) + tok * XDW;
    const float* w = (dir ? b_dt_w : f_dt_w) + d * DTR;
    float acc = (dir ? b_dt_b : f_dt_b)[d];
    #pragma unroll
    for (int q = 0; q < DTR; ++q) acc = fmaf(xd[q], w[q], acc);
    float sp = fmaxf(acc, 0.f) + log1pf(__expf(-fabsf(acc)));
    (dir ? dlT_b : dlT_f)[j] = sp;
}

// ---------------- K5: chunked selective scan ----------------
// Block: 256 threads = 2 chains x 8 chunks x 16 states.
// Phase A: per-chunk local scan (h0=0) -> (P, h_end) in LDS.
// Phase B: 8-step serial combine -> h_init per chunk.
// Phase C: rescan with h_init, reduce over n, store y (tok-major).
__global__ __launch_bounds__(256) void scan_kernel(
        const float* __restrict__ dlT_f, const float* __restrict__ dlT_b,
        const float* __restrict__ xc_f, const float* __restrict__ xc_b,
        const float* __restrict__ xd_f, const float* __restrict__ xd_b,
        float* __restrict__ ys_f, float* __restrict__ ys_b,
        const float* __restrict__ fA, const float* __restrict__ bA) {
    __shared__ float sP[2][8][16];
    __shared__ float sH[2][8][16];
    __shared__ float sI[2][8][16];
    const int tid = threadIdx.x;
    const int cl = tid >> 7;
    const int c  = (tid >> 4) & 7;
    const int n  = tid & 15;
    const int chain = blockIdx.x * 2 + cl;        // < 2*CH
    const int dir = chain >= CH;
    const int r = dir ? chain - CH : chain;
    const int b = r / DI, d = r - (r / DI) * DI;

    const float* dlT = (dir ? dlT_b : dlT_f) + ((size_t)r << 10);
    const float* ub  = (dir ? xc_b : xc_f) + ((size_t)b << 10) * DI + d;
    const float* xdb = (dir ? xd_b : xd_f) + ((size_t)b << 10) * XDW;
    float* yb        = (dir ? ys_b : ys_f) + ((size_t)b << 10) * DI + d;
    const float Av = -__expf((dir ? bA : fA)[d * DS + n]);

    const int t0 = c << 7;                        // chunk start

    // ---- phase A ----
    if (c < 7) {
        float h = 0.f, S = 0.f;
        const float* dp = dlT + t0;
        const float* up = ub + (size_t)t0 * DI;
        const float* Bp = xdb + (size_t)t0 * XDW + DTR + n;
        float4 d4 = *(const float4*)dp;
        float u4[4], B4[4];
        #pragma unroll
        for (int i = 0; i < 4; ++i) {
            u4[i] = up[(size_t)i * DI];
            B4[i] = Bp[(size_t)i * XDW];
        }
        for (int g = 0; g < 32; ++g) {
            float4 d4n = d4; float u4n[4], B4n[4];
            if (g < 31) {
                d4n = *(const float4*)(dp + 4 * (g + 1));
                #pragma unroll
                for (int i = 0; i < 4; ++i) {
                    u4n[i] = up[(size_t)(4 * (g + 1) + i) * DI];
                    B4n[i] = Bp[(size_t)(4 * (g + 1) + i) * XDW];
                }
            } else {
                #pragma unroll
                for (int i = 0; i < 4; ++i) { u4n[i] = 0.f; B4n[i] = 0.f; }
            }
            float dv[4] = {d4.x, d4.y, d4.z, d4.w};
            #pragma unroll
            for (int i = 0; i < 4; ++i) {
                float dA = __expf(dv[i] * Av);
                h = fmaf(dA, h, dv[i] * u4[i] * B4[i]);
                S += dv[i];
            }
            d4 = d4n;
            #pragma unroll
            for (int i = 0; i < 4; ++i) { u4[i] = u4n[i]; B4[i] = B4n[i]; }
        }
        sP[cl][c][n] = __expf(S * Av);
        sH[cl][c][n] = h;
    }
    __syncthreads();

    // ---- phase B ----
    if (c == 0) {
        float hi = 0.f;
        #pragma unroll
        for (int cc = 0; cc < 8; ++cc) {
            sI[cl][cc][n] = hi;
            if (cc < 7) hi = sH[cl][cc][n] + sP[cl][cc][n] * hi;
        }
    }
    __syncthreads();

    // ---- phase C ----
    {
        float h = sI[cl][c][n];
        const float* dp = dlT + t0;
        const float* up = ub + (size_t)t0 * DI;
        const float* Bp = xdb + (size_t)t0 * XDW + DTR + n;
        const float* Cp = Bp + DS;
        float* yp = yb + (size_t)t0 * DI;
        float4 d4 = *(const float4*)dp;
        float u4[4], B4[4], C4[4];
        #pragma unroll
        for (int i = 0; i < 4; ++i) {
            u4[i] = up[(size_t)i * DI];
            B4[i] = Bp[(size_t)i * XDW];
            C4[i] = Cp[(size_t)i * XDW];
        }
        for (int g = 0; g < 32; ++g) {
            float4 d4n = d4; float u4n[4], B4n[4], C4n[4];
            if (g < 31) {
                d4n = *(const float4*)(dp + 4 * (g + 1));
                #pragma unroll
                for (int i = 0; i < 4; ++i) {
                    u4n[i] = up[(size_t)(4 * (g + 1) + i) * DI];
                    B4n[i] = Bp[(size_t)(4 * (g + 1) + i) * XDW];
                    C4n[i] = Cp[(size_t)(4 * (g + 1) + i) * XDW];
                }
            } else {
                #pragma unroll
                for (int i = 0; i < 4; ++i) { u4n[i] = 0.f; B4n[i] = 0.f; C4n[i] = 0.f; }
            }
            float dv[4] = {d4.x, d4.y, d4.z, d4.w};
            #pragma unroll
            for (int i = 0; i < 4; ++i) {
                float dA = __expf(dv[i] * Av);
                h = fmaf(dA, h, dv[i] * u4[i] * B4[i]);
                float p = h * C4[i];
                p += __shfl_xor(p, 1);
                p += __shfl_xor(p, 2);
                p += __shfl_xor(p, 4);
                p += __shfl_xor(p, 8);
                if (n == 0) yp[(size_t)(4 * g + i) * DI] = p;
            }
            d4 = d4n;
            #pragma unroll
            for (int i = 0; i < 4; ++i) { u4[i] = u4n[i]; B4[i] = B4n[i]; C4[i] = C4n[i]; }
        }
    }
}

// ---------------- K6: gate: ys = (ys + D*xc) * silu(z), in place, both dirs ----------------
__global__ __launch_bounds__(256) void gate_kernel(
        float* __restrict__ ys_f, float* __restrict__ ys_b,
        const float* __restrict__ xc_f, const float* __restrict__ xc_b,
        const float* __restrict__ z_f, const float* __restrict__ z_b,
        const float* __restrict__ fD, const float* __restrict__ bD) {
    int i = blockIdx.x * 256 + threadIdx.x;
    int dir = i >= (int)DI_SZ;
    int j = dir ? i - (int)DI_SZ : i;
    int tok = j / DI;
    int d = j - tok * DI;
    float* ys = dir ? ys_b : ys_f;
    float y = ys[j] + (dir ? bD : fD)[d] * (dir ? xc_b : xc_f)[j];
    float z = (dir ? z_b : z_f)[j];
    ys[j] = y * siluf(z);
}

// ---------------- K7b: init d_out to cls_b ----------------
__global__ void out_init(float* __restrict__ out, const float* __restrict__ cls_b) {
    if (threadIdx.x < B_) out[threadIdx.x] = cls_b[0];
}

// ---------------- K8: combine, LN, SiLU, residual, cls head ----------------
__global__ __launch_bounds__(256) void final_kernel(
        const float* __restrict__ fo, const float* __restrict__ bo,
        const float* __restrict__ h, const float* __restrict__ g,
        const float* __restrict__ bb, const float* __restrict__ cls_w,
        float* __restrict__ out) {
    __shared__ float red[4];
    const int t = blockIdx.x;
    const int b = t >> 10, l = t & 1023;
    const int e = threadIdx.x;
    float v = 0.f;
    if (e < DM)
        v = 0.5f * (fo[(size_t)t * DM + e] + bo[((size_t)b * L_ + (L_ - 1 - l)) * DM + e]);
    float s1 = blk_sum(v, red);
    float s2 = blk_sum(v * v, red);
    float mean = s1 * (1.f / DM);
    float var = s2 * (1.f / DM) - mean * mean;
    float inv = rsqrtf(var + 1e-5f);
    float c = 0.f;
    if (e < DM) {
        float o = (v - mean) * inv * g[e] + bb[e];
        o = siluf(o) + h[(size_t)t * DM + e];
        c = o * cls_w[e];
    }
    float s = blk_sum(c, red);
    if (e == 0) atomicAdd(&out[b], s * (1.f / 1024.f));
}

// ---------------- launch ----------------
extern "C" void kernel_launch(void* const* d_in, const int* in_sizes, int n_in,
                              void* d_out, int out_size, void* d_ws, size_t ws_size,
                              hipStream_t stream) {
    const float* x        = (const float*)d_in[0];
    const float* patch_w  = (const float*)d_in[1];
    const float* patch_b  = (const float*)d_in[2];
    const float* pe_g     = (const float*)d_in[3];
    const float* pe_b     = (const float*)d_in[4];
    const float* blk_g    = (const float*)d_in[5];
    const float* blk_b    = (const float*)d_in[6];
    const float* cls_w    = (const float*)d_in[7];
    const float* cls_b    = (const float*)d_in[8];
    const float* f_in_w   = (const float*)d_in[9];
    const float* f_conv_w = (const float*)d_in[10];
    const float* f_conv_b = (const float*)d_in[11];
    const float* f_xp_w   = (const float*)d_in[12];
    const float* f_dt_w   = (const float*)d_in[13];
    const float* f_dt_b   = (const float*)d_in[14];
    const float* f_A_log  = (const float*)d_in[15];
    const float* f_D      = (const float*)d_in[16];
    const float* f_out_w  = (const float*)d_in[17];
    const float* b_in_w   = (const float*)d_in[18];
    const float* b_conv_w = (const float*)d_in[19];
    const float* b_conv_b = (const float*)d_in[20];
    const float* b_xp_w   = (const float*)d_in[21];
    const float* b_dt_w   = (const float*)d_in[22];
    const float* b_dt_b   = (const float*)d_in[23];
    const float* b_A_log  = (const float*)d_in[24];
    const float* b_D      = (const float*)d_in[25];
    const float* b_out_w  = (const float*)d_in[26];

    float* ws = (float*)d_ws;
    float* out = (float*)d_out;

    float* Hb   = ws + O_H;
    float* XIf  = ws + O_XI_F;   // xi_f -> deltaT_f -> fo
    float* XIb  = ws + O_XI_B;   // xi_b -> deltaT_b -> bo
    float* Zf   = ws + O_Z_F;
    float* Zb   = ws + O_Z_B;
    float* XCf  = ws + O_XC_F;
    float* XCb  = ws + O_XC_B;
    float* XDf  = ws + O_XD_F;
    float* XDb  = ws + O_XD_B;
    float* YSf  = ws + O_YS_F;   // early: Xp temp
    float* YSb  = ws + O_YS_B;   // early: tok_raw temp

    // K0: gather patches
    gather_patch<<<(NTOK * 192) / 256, 256, 0, stream>>>(x, YSf);
    // K1: tok = Xp @ patch_w^T + patch_b
    gemm_xt<<<dim3(NTOK / 64, 3), 256, 0, stream>>>(YSf, patch_w, patch_b, YSb,
                                                    NTOK, E_, 192, E_, 0);
    // K1b: LN + SiLU + pos -> h
    ln_silu_pos<<<NTOK, 256, 0, stream>>>(YSb, pe_g, pe_b, Hb);
    // K2: xz GEMMs (xi and z halves, fwd and flipped-bwd)
    gemm_xt<<<dim3(NTOK / 64, 7), 256, 0, stream>>>(Hb, f_in_w, nullptr, XIf,
                                                    NTOK, DI, DM, DI, 0);
    gemm_xt<<<dim3(NTOK / 64, 7), 256, 0, stream>>>(Hb, f_in_w + (size_t)DI * DM, nullptr, Zf,
                                                    NTOK, DI, DM, DI, 0);
    gemm_xt<<<dim3(NTOK / 64, 7), 256, 0, stream>>>(Hb, b_in_w, nullptr, XIb,
                                                    NTOK, DI, DM, DI, 1);
    gemm_xt<<<dim3(NTOK / 64, 7), 256, 0, stream>>>(Hb, b_in_w + (size_t)DI * DM, nullptr, Zb,
                                                    NTOK, DI, DM, DI, 1);
    // K3: conv + silu
    conv_silu_kernel<<<(2 * (int)DI_SZ) / 256, 256, 0, stream>>>(
        XIf, XIb, XCf, XCb, f_conv_w, f_conv_b, b_conv_w, b_conv_b);
    // K2b: x_dbl GEMMs
    gemm_xt<<<dim3(NTOK / 64, 1), 256, 0, stream>>>(XCf, f_xp_w, nullptr, XDf,
                                                    NTOK, XDW, DI, XDW, 0);
    gemm_xt<<<dim3(NTOK / 64, 1), 256, 0, stream>>>(XCb, b_xp_w, nullptr, XDb,
                                                    NTOK, XDW, DI, XDW, 0);
    // K4: delta, transposed output (overwrites dead xi regions)
    delta_kernel<<<(2 * (int)DI_SZ) / 256, 256, 0, stream>>>(
        XDf, XDb, XIf, XIb, f_dt_w, f_dt_b, b_dt_w, b_dt_b);
    // K5: chunked selective scan (2 chains per block)
    scan_kernel<<<CH, 256, 0, stream>>>(
        XIf, XIb, XCf, XCb, XDf, XDb, YSf, YSb, f_A_log, b_A_log);
    // K6: gating in place
    gate_kernel<<<(2 * (int)DI_SZ) / 256, 256, 0, stream>>>(
        YSf, YSb, XCf, XCb, Zf, Zb, f_D, b_D);
    // K7: out projections (write over deltaT regions -> fo/bo)
    gemm_xt<<<dim3(NTOK / 64, 4), 256, 0, stream>>>(YSf, f_out_w, nullptr, XIf,
                                                    NTOK, DM, DI, DM, 0);
    gemm_xt<<<dim3(NTOK / 64, 4), 256, 0, stream>>>(YSb, b_out_w, nullptr, XIb,
                                                    NTOK, DM, DI, DM, 0);
    // K7b + K8: init out, then accumulate head
    out_init<<<1, 64, 0, stream>>>(out, cls_b);
    final_kernel<<<NTOK, 256, 0, stream>>>(XIf, XIb, Hb, blk_g, blk_b, cls_w, out);
}

// Round 3
// 1154.497 us; speedup vs baseline: 1.2656x; 1.2275x over previous
//
#include <hip/hip_runtime.h>
#include <cstdint>
#include <cstddef>

// ---------------- problem constants ----------------
constexpr int B_   = 16;
constexpr int L_   = 1024;
constexpr int E_   = 192;
constexpr int DM   = 196;   // D_MODEL
constexpr int DI   = 392;   // D_INNER
constexpr int DS   = 16;    // D_STATE
constexpr int DTR  = 13;    // DT_RANK
constexpr int NTOK = B_ * L_;            // 16384
constexpr int XDW  = DTR + 2 * DS;       // 45
constexpr int CH   = B_ * DI;            // 6272 chains per direction

constexpr size_t HW_SZ = (size_t)NTOK * DM;   // 3,211,264
constexpr size_t DI_SZ = (size_t)NTOK * DI;   // 6,422,528
constexpr size_t XD_SZ = (size_t)NTOK * XDW;  //   737,280

// ---------------- workspace layout (float offsets) ----------------
// XI regions: xiT -> dlT -> fo/bo (tok-major)
// YS regions: early Xp/tok_raw temps, then ysT (gated, chain-major)
constexpr size_t O_H    = 0;
constexpr size_t O_XI_F = O_H    + HW_SZ;
constexpr size_t O_XI_B = O_XI_F + DI_SZ;
constexpr size_t O_Z_F  = O_XI_B + DI_SZ;
constexpr size_t O_Z_B  = O_Z_F  + DI_SZ;
constexpr size_t O_XC_F = O_Z_B  + DI_SZ;
constexpr size_t O_XC_B = O_XC_F + DI_SZ;
constexpr size_t O_XD_F = O_XC_B + DI_SZ;
constexpr size_t O_XD_B = O_XD_F + XD_SZ;
constexpr size_t O_YS_F = O_XD_B + XD_SZ;
constexpr size_t O_YS_B = O_YS_F + DI_SZ;

// ---------------- helpers ----------------
__device__ __forceinline__ float siluf(float x) {
    return x / (1.f + __expf(-x));
}

__device__ __forceinline__ float blk_sum(float v, float* red) {
    #pragma unroll
    for (int o = 32; o > 0; o >>= 1) v += __shfl_down(v, o);
    int w = threadIdx.x >> 6;
    __syncthreads();
    if ((threadIdx.x & 63) == 0) red[w] = v;
    __syncthreads();
    return red[0] + red[1] + red[2] + red[3];
}

// ---------------- K0: gather patches into (NTOK, 192) ----------------
__global__ __launch_bounds__(256) void gather_patch(const float* __restrict__ x,
                                                    float* __restrict__ Xp) {
    int i = blockIdx.x * 256 + threadIdx.x;
    int tok = i / 192, r = i - tok * 192;
    int c = r >> 6, pq = r & 63, p = pq >> 3, q = pq & 7;
    int b = tok >> 10, l = tok & 1023, hh = l >> 5, wv = l & 31;
    Xp[i] = x[(((size_t)(b * 3 + c) * 256 + hh * 8 + p) << 8) + wv * 8 + q];
}

// ---------------- generic fp32 GEMM: C(M,N) = A(M,K) @ W(N,K)^T (+bias) ----------------
// flags bit0: flip A rows within each batch of 1024 (tok-major A only)
// flags bit1: A is chain-major: A[(b*K + k)*1024 + t], m = b*1024 + t
// flags bit2: store C chain-major: C[(b*N + n)*1024 + t]
__global__ __launch_bounds__(256) void gemm_xt(const float* __restrict__ A,
                                               const float* __restrict__ W,
                                               const float* __restrict__ bias,
                                               float* __restrict__ C,
                                               int M, int N, int K, int ldc, int flags) {
    __shared__ __align__(16) float As[16][68];
    __shared__ __align__(16) float Ws[16][68];
    const int m0 = blockIdx.x * 64, n0 = blockIdx.y * 64;
    const int t = threadIdx.x;
    const int tx = t & 15, ty = t >> 4;
    float acc[4][4] = {};
    const int KT = (K + 15) >> 4;

    const int arow_l = t >> 2;          // 0..63
    const int kq = (t & 3) * 4;         // 0,4,8,12
    const int bb_ = m0 >> 10, tt0 = m0 & 1023;   // batch / t-offset (tiles never cross batch)

    for (int kt = 0; kt < KT; ++kt) {
        const int k0 = kt << 4;
        if (flags & 2) {
            // chain-major A: 16 k-rows x 64 t; thread (kr=t>>4, tc=t&15) loads float4
            int kr = t >> 4, tc = t & 15;
            int kk = k0 + kr;
            float4 v = {0.f, 0.f, 0.f, 0.f};
            if (kk < K)
                v = *(const float4*)(A + (((size_t)bb_ * K + kk) << 10) + tt0 + tc * 4);
            *(float4*)&As[kr][tc * 4] = v;
        } else {
            int ar = m0 + arow_l;
            int am = (flags & 1) ? ((ar & ~1023) + 1023 - (ar & 1023)) : ar;
            const float* ap = A + (size_t)am * K;
            #pragma unroll
            for (int jj = 0; jj < 4; ++jj) {
                int kk = k0 + kq + jj;
                As[kq + jj][arow_l] = (kk < K) ? ap[kk] : 0.f;
            }
        }
        {
            int wr = n0 + arow_l;
            const float* wp = W + (size_t)wr * K;
            bool okn = (wr < N);
            #pragma unroll
            for (int jj = 0; jj < 4; ++jj) {
                int kk = k0 + kq + jj;
                Ws[kq + jj][arow_l] = (okn && kk < K) ? wp[kk] : 0.f;
            }
        }
        __syncthreads();
        #pragma unroll
        for (int k = 0; k < 16; ++k) {
            float av[4], wv[4];
            *reinterpret_cast<float4*>(av) = *reinterpret_cast<const float4*>(&As[k][ty * 4]);
            *reinterpret_cast<float4*>(wv) = *reinterpret_cast<const float4*>(&Ws[k][tx * 4]);
            #pragma unroll
            for (int i = 0; i < 4; ++i)
                #pragma unroll
                for (int j = 0; j < 4; ++j)
                    acc[i][j] = fmaf(av[i], wv[j], acc[i][j]);
        }
        __syncthreads();
    }
    if (flags & 4) {
        // chain-major store: float4 along t
        #pragma unroll
        for (int j = 0; j < 4; ++j) {
            int n = n0 + tx * 4 + j;
            if (n < N) {
                float4 v = {acc[0][j], acc[1][j], acc[2][j], acc[3][j]};
                if (bias) {
                    float bv = bias[n];
                    v.x += bv; v.y += bv; v.z += bv; v.w += bv;
                }
                *(float4*)(C + (((size_t)bb_ * N + n) << 10) + tt0 + ty * 4) = v;
            }
        }
    } else {
        #pragma unroll
        for (int i = 0; i < 4; ++i) {
            int m = m0 + ty * 4 + i;
            #pragma unroll
            for (int j = 0; j < 4; ++j) {
                int n = n0 + tx * 4 + j;
                if (n < N) {
                    float v = acc[i][j];
                    if (bias) v += bias[n];
                    C[(size_t)m * ldc + n] = v;
                }
            }
        }
    }
}

// ---------------- K1b: LN + SiLU + positional features -> h (NTOK, 196) ----------------
__global__ __launch_bounds__(256) void ln_silu_pos(const float* __restrict__ tok,
                                                   const float* __restrict__ g,
                                                   const float* __restrict__ bb,
                                                   float* __restrict__ h) {
    __shared__ float red[4];
    const int t = blockIdx.x;
    const int e = threadIdx.x;
    float v = (e < E_) ? tok[(size_t)t * E_ + e] : 0.f;
    float s1 = blk_sum(v, red);
    float s2 = blk_sum(v * v, red);
    float mean = s1 * (1.f / E_);
    float var = s2 * (1.f / E_) - mean * mean;
    float inv = rsqrtf(var + 1e-5f);
    if (e < E_) {
        float o = (v - mean) * inv * g[e] + bb[e];
        h[(size_t)t * DM + e] = siluf(o);
    } else if (e < DM) {
        const int l = t & 1023;
        const float scale = 0.19634954084936207f;  // 2*pi/32
        float pv;
        if (e == E_)          pv = sinf(l * scale);
        else if (e == E_ + 1) pv = cosf(l * scale);
        else if (e == E_ + 2) pv = sinf((float)(l >> 5) * scale);
        else                  pv = cosf((float)(l >> 5) * scale);
        h[(size_t)t * DM + e] = pv;
    }
}

// ---------------- K3: depthwise causal conv(4)+SiLU in chain-major ----------------
__global__ __launch_bounds__(256) void conv_silu_T(
        const float* __restrict__ xiT_f, const float* __restrict__ xiT_b,
        float* __restrict__ xcT_f, float* __restrict__ xcT_b,
        const float* __restrict__ fw, const float* __restrict__ fb,
        const float* __restrict__ bw, const float* __restrict__ bb2) {
    int i = blockIdx.x * 256 + threadIdx.x;        // < 2*CH*256
    int rall = i >> 8;
    int dir = rall >= CH;
    int r = rall - (dir ? CH : 0);
    int d = r % DI;
    int t0 = (i & 255) << 2;
    const float* xi = (dir ? xiT_b : xiT_f) + ((size_t)r << 10) + t0;
    float cur[4], prev[4] = {0.f, 0.f, 0.f, 0.f};
    *(float4*)cur = *(const float4*)xi;
    if (t0) *(float4*)prev = *(const float4*)(xi - 4);
    const float* w = (dir ? bw : fw) + d * 4;
    float bias = (dir ? bb2 : fb)[d];
    float xv[7] = {prev[1], prev[2], prev[3], cur[0], cur[1], cur[2], cur[3]};
    float o[4];
    #pragma unroll
    for (int tt = 0; tt < 4; ++tt) {
        float a = bias;
        #pragma unroll
        for (int k = 0; k < 4; ++k) a = fmaf(xv[tt + k], w[k], a);
        o[tt] = siluf(a);
    }
    *(float4*)((dir ? xcT_b : xcT_f) + ((size_t)r << 10) + t0) = *(float4*)o;
}

// ---------------- K4: delta = softplus(dt @ dt_w^T + dt_b), chain-major out ----------------
__global__ __launch_bounds__(256) void delta_kernel(
        const float* __restrict__ xd_f, const float* __restrict__ xd_b,
        float* __restrict__ dlT_f, float* __restrict__ dlT_b,
        const float* __restrict__ f_dt_w, const float* __restrict__ f_dt_b,
        const float* __restrict__ b_dt_w, const float* __restrict__ b_dt_b) {
    int i = blockIdx.x * 256 + threadIdx.x;       // < 2*DI_SZ
    int dir = i >= (int)DI_SZ;
    int j = dir ? i - (int)DI_SZ : i;             // r*1024 + t
    int r = j >> 10, t = j & 1023;
    int b = r / DI, d = r - (r / DI) * DI;
    size_t tok = ((size_t)b << 10) + t;
    const float* xd = (dir ? xd_b : xd_f) + tok * XDW;
    const float* w = (dir ? b_dt_w : f_dt_w) + d * DTR;
    float acc = (dir ? b_dt_b : f_dt_b)[d];
    #pragma unroll
    for (int q = 0; q < DTR; ++q) acc = fmaf(xd[q], w[q], acc);
    float sp = fmaxf(acc, 0.f) + log1pf(__expf(-fabsf(acc)));
    (dir ? dlT_b : dlT_f)[j] = sp;
}

// ---------------- K5: chunked selective scan + fused gate ----------------
// Block: 256 threads = 2 chains x 8 chunks x 16 states.
__global__ __launch_bounds__(256) void scan_kernel(
        const float* __restrict__ dlT_f, const float* __restrict__ dlT_b,
        const float* __restrict__ xcT_f, const float* __restrict__ xcT_b,
        const float* __restrict__ xd_f, const float* __restrict__ xd_b,
        const float* __restrict__ zT_f, const float* __restrict__ zT_b,
        float* __restrict__ ysT_f, float* __restrict__ ysT_b,
        const float* __restrict__ fA, const float* __restrict__ bA,
        const float* __restrict__ fD, const float* __restrict__ bD) {
    __shared__ float sP[2][8][16];
    __shared__ float sH[2][8][16];
    __shared__ float sI[2][8][16];
    const int tid = threadIdx.x;
    const int cl = tid >> 7;
    const int c  = (tid >> 4) & 7;
    const int n  = tid & 15;
    const int chain = blockIdx.x * 2 + cl;
    const int dir = chain >= CH;
    const int r = dir ? chain - CH : chain;
    const int b = r / DI, d = r - (r / DI) * DI;

    const float* dlT = (dir ? dlT_b : dlT_f) + ((size_t)r << 10);
    const float* uT  = (dir ? xcT_b : xcT_f) + ((size_t)r << 10);
    const float* xdb = (dir ? xd_b : xd_f) + ((size_t)b << 10) * XDW;
    const float* zT  = (dir ? zT_b : zT_f) + ((size_t)r << 10);
    float* yT        = (dir ? ysT_b : ysT_f) + ((size_t)r << 10);
    const float Av = -__expf((dir ? bA : fA)[d * DS + n]);
    const float Dd = (dir ? bD : fD)[d];

    const int t0 = c << 7;                        // chunk start

    // ---- phase A: local scan, h0 = 0 ----
    if (c < 7) {
        float h = 0.f, S = 0.f;
        const float* dp = dlT + t0;
        const float* up = uT + t0;
        const float* Bp = xdb + (size_t)t0 * XDW + DTR + n;
        float4 d4 = *(const float4*)dp;
        float4 u4 = *(const float4*)up;
        float B4[4];
        #pragma unroll
        for (int i = 0; i < 4; ++i) B4[i] = Bp[(size_t)i * XDW];
        for (int g = 0; g < 32; ++g) {
            float4 d4n = d4, u4n = u4;
            float B4n[4];
            if (g < 31) {
                d4n = *(const float4*)(dp + 4 * (g + 1));
                u4n = *(const float4*)(up + 4 * (g + 1));
                #pragma unroll
                for (int i = 0; i < 4; ++i) B4n[i] = Bp[(size_t)(4 * (g + 1) + i) * XDW];
            } else {
                #pragma unroll
                for (int i = 0; i < 4; ++i) B4n[i] = 0.f;
            }
            float dv[4] = {d4.x, d4.y, d4.z, d4.w};
            float uv[4] = {u4.x, u4.y, u4.z, u4.w};
            #pragma unroll
            for (int i = 0; i < 4; ++i) {
                float dA = __expf(dv[i] * Av);
                h = fmaf(dA, h, dv[i] * uv[i] * B4[i]);
                S += dv[i];
            }
            d4 = d4n; u4 = u4n;
            #pragma unroll
            for (int i = 0; i < 4; ++i) B4[i] = B4n[i];
        }
        sP[cl][c][n] = __expf(S * Av);
        sH[cl][c][n] = h;
    }
    __syncthreads();

    // ---- phase B: serial combine ----
    if (c == 0) {
        float hi = 0.f;
        #pragma unroll
        for (int cc = 0; cc < 8; ++cc) {
            sI[cl][cc][n] = hi;
            if (cc < 7) hi = sH[cl][cc][n] + sP[cl][cc][n] * hi;
        }
    }
    __syncthreads();

    // ---- phase C: rescan with h_init, reduce over n, gate, store ----
    {
        float h = sI[cl][c][n];
        const float* dp = dlT + t0;
        const float* up = uT + t0;
        const float* Bp = xdb + (size_t)t0 * XDW + DTR + n;
        const float* Cp = Bp + DS;
        const float* zp = zT + t0;
        float* yp = yT + t0;
        float4 d4 = *(const float4*)dp;
        float4 u4 = *(const float4*)up;
        float B4[4], C4[4];
        #pragma unroll
        for (int i = 0; i < 4; ++i) {
            B4[i] = Bp[(size_t)i * XDW];
            C4[i] = Cp[(size_t)i * XDW];
        }
        for (int g = 0; g < 32; ++g) {
            float4 d4n = d4, u4n = u4;
            float B4n[4], C4n[4];
            if (g < 31) {
                d4n = *(const float4*)(dp + 4 * (g + 1));
                u4n = *(const float4*)(up + 4 * (g + 1));
                #pragma unroll
                for (int i = 0; i < 4; ++i) {
                    B4n[i] = Bp[(size_t)(4 * (g + 1) + i) * XDW];
                    C4n[i] = Cp[(size_t)(4 * (g + 1) + i) * XDW];
                }
            } else {
                #pragma unroll
                for (int i = 0; i < 4; ++i) { B4n[i] = 0.f; C4n[i] = 0.f; }
            }
            float dv[4] = {d4.x, d4.y, d4.z, d4.w};
            float uv[4] = {u4.x, u4.y, u4.z, u4.w};
            float p4[4];
            #pragma unroll
            for (int i = 0; i < 4; ++i) {
                float dA = __expf(dv[i] * Av);
                h = fmaf(dA, h, dv[i] * uv[i] * B4[i]);
                float p = h * C4[i];
                p += __shfl_xor(p, 1);
                p += __shfl_xor(p, 2);
                p += __shfl_xor(p, 4);
                p += __shfl_xor(p, 8);
                p4[i] = p;
            }
            if (n == 0) {
                float4 z4 = *(const float4*)(zp + 4 * g);
                float4 yv;
                yv.x = (p4[0] + Dd * uv[0]) * siluf(z4.x);
                yv.y = (p4[1] + Dd * uv[1]) * siluf(z4.y);
                yv.z = (p4[2] + Dd * uv[2]) * siluf(z4.z);
                yv.w = (p4[3] + Dd * uv[3]) * siluf(z4.w);
                *(float4*)(yp + 4 * g) = yv;
            }
            d4 = d4n; u4 = u4n;
            #pragma unroll
            for (int i = 0; i < 4; ++i) { B4[i] = B4n[i]; C4[i] = C4n[i]; }
        }
    }
}

// ---------------- K7b: init d_out to cls_b ----------------
__global__ void out_init(float* __restrict__ out, const float* __restrict__ cls_b) {
    if (threadIdx.x < B_) out[threadIdx.x] = cls_b[0];
}

// ---------------- K8: combine, LN, SiLU, residual, cls head ----------------
__global__ __launch_bounds__(256) void final_kernel(
        const float* __restrict__ fo, const float* __restrict__ bo,
        const float* __restrict__ h, const float* __restrict__ g,
        const float* __restrict__ bb, const float* __restrict__ cls_w,
        float* __restrict__ out) {
    __shared__ float red[4];
    const int t = blockIdx.x;
    const int b = t >> 10, l = t & 1023;
    const int e = threadIdx.x;
    float v = 0.f;
    if (e < DM)
        v = 0.5f * (fo[(size_t)t * DM + e] + bo[((size_t)b * L_ + (L_ - 1 - l)) * DM + e]);
    float s1 = blk_sum(v, red);
    float s2 = blk_sum(v * v, red);
    float mean = s1 * (1.f / DM);
    float var = s2 * (1.f / DM) - mean * mean;
    float inv = rsqrtf(var + 1e-5f);
    float c = 0.f;
    if (e < DM) {
        float o = (v - mean) * inv * g[e] + bb[e];
        o = siluf(o) + h[(size_t)t * DM + e];
        c = o * cls_w[e];
    }
    float s = blk_sum(c, red);
    if (e == 0) atomicAdd(&out[b], s * (1.f / 1024.f));
}

// ---------------- launch ----------------
extern "C" void kernel_launch(void* const* d_in, const int* in_sizes, int n_in,
                              void* d_out, int out_size, void* d_ws, size_t ws_size,
                              hipStream_t stream) {
    const float* x        = (const float*)d_in[0];
    const float* patch_w  = (const float*)d_in[1];
    const float* patch_b  = (const float*)d_in[2];
    const float* pe_g     = (const float*)d_in[3];
    const float* pe_b     = (const float*)d_in[4];
    const float* blk_g    = (const float*)d_in[5];
    const float* blk_b    = (const float*)d_in[6];
    const float* cls_w    = (const float*)d_in[7];
    const float* cls_b    = (const float*)d_in[8];
    const float* f_in_w   = (const float*)d_in[9];
    const float* f_conv_w = (const float*)d_in[10];
    const float* f_conv_b = (const float*)d_in[11];
    const float* f_xp_w   = (const float*)d_in[12];
    const float* f_dt_w   = (const float*)d_in[13];
    const float* f_dt_b   = (const float*)d_in[14];
    const float* f_A_log  = (const float*)d_in[15];
    const float* f_D      = (const float*)d_in[16];
    const float* f_out_w  = (const float*)d_in[17];
    const float* b_in_w   = (const float*)d_in[18];
    const float* b_conv_w = (const float*)d_in[19];
    const float* b_conv_b = (const float*)d_in[20];
    const float* b_xp_w   = (const float*)d_in[21];
    const float* b_dt_w   = (const float*)d_in[22];
    const float* b_dt_b   = (const float*)d_in[23];
    const float* b_A_log  = (const float*)d_in[24];
    const float* b_D      = (const float*)d_in[25];
    const float* b_out_w  = (const float*)d_in[26];

    float* ws = (float*)d_ws;
    float* out = (float*)d_out;

    float* Hb   = ws + O_H;
    float* XIf  = ws + O_XI_F;   // xiT_f -> dlT_f -> fo
    float* XIb  = ws + O_XI_B;   // xiT_b -> dlT_b -> bo
    float* Zf   = ws + O_Z_F;    // zT_f
    float* Zb   = ws + O_Z_B;    // zT_b
    float* XCf  = ws + O_XC_F;   // xcT_f
    float* XCb  = ws + O_XC_B;   // xcT_b
    float* XDf  = ws + O_XD_F;
    float* XDb  = ws + O_XD_B;
    float* YSf  = ws + O_YS_F;   // early: Xp temp; later ysT_f (gated)
    float* YSb  = ws + O_YS_B;   // early: tok_raw temp; later ysT_b

    // K0: gather patches
    gather_patch<<<(NTOK * 192) / 256, 256, 0, stream>>>(x, YSf);
    // K1: tok = Xp @ patch_w^T + patch_b  (tok-major)
    gemm_xt<<<dim3(NTOK / 64, 3), 256, 0, stream>>>(YSf, patch_w, patch_b, YSb,
                                                    NTOK, E_, 192, E_, 0);
    // K1b: LN + SiLU + pos -> h
    ln_silu_pos<<<NTOK, 256, 0, stream>>>(YSb, pe_g, pe_b, Hb);
    // K2: xz GEMMs -> chain-major xiT / zT (flags: 4 = CT store, +1 flip for bwd)
    gemm_xt<<<dim3(NTOK / 64, 7), 256, 0, stream>>>(Hb, f_in_w, nullptr, XIf,
                                                    NTOK, DI, DM, 0, 4);
    gemm_xt<<<dim3(NTOK / 64, 7), 256, 0, stream>>>(Hb, f_in_w + (size_t)DI * DM, nullptr, Zf,
                                                    NTOK, DI, DM, 0, 4);
    gemm_xt<<<dim3(NTOK / 64, 7), 256, 0, stream>>>(Hb, b_in_w, nullptr, XIb,
                                                    NTOK, DI, DM, 0, 5);
    gemm_xt<<<dim3(NTOK / 64, 7), 256, 0, stream>>>(Hb, b_in_w + (size_t)DI * DM, nullptr, Zb,
                                                    NTOK, DI, DM, 0, 5);
    // K3: conv + silu in chain-major
    conv_silu_T<<<2 * CH, 256, 0, stream>>>(XIf, XIb, XCf, XCb,
                                            f_conv_w, f_conv_b, b_conv_w, b_conv_b);
    // K2b: x_dbl GEMMs (A chain-major = flags 2, store tok-major)
    gemm_xt<<<dim3(NTOK / 64, 1), 256, 0, stream>>>(XCf, f_xp_w, nullptr, XDf,
                                                    NTOK, XDW, DI, XDW, 2);
    gemm_xt<<<dim3(NTOK / 64, 1), 256, 0, stream>>>(XCb, b_xp_w, nullptr, XDb,
                                                    NTOK, XDW, DI, XDW, 2);
    // K4: delta -> dlT (overwrites dead xiT regions)
    delta_kernel<<<(2 * (int)DI_SZ) / 256, 256, 0, stream>>>(
        XDf, XDb, XIf, XIb, f_dt_w, f_dt_b, b_dt_w, b_dt_b);
    // K5: chunked scan + fused gate -> ysT
    scan_kernel<<<CH, 256, 0, stream>>>(
        XIf, XIb, XCf, XCb, XDf, XDb, Zf, Zb, YSf, YSb,
        f_A_log, b_A_log, f_D, b_D);
    // K7: out projections (A chain-major, store tok-major) -> fo/bo
    gemm_xt<<<dim3(NTOK / 64, 4), 256, 0, stream>>>(YSf, f_out_w, nullptr, XIf,
                                                    NTOK, DM, DI, DM, 2);
    gemm_xt<<<dim3(NTOK / 64, 4), 256, 0, stream>>>(YSb, b_out_w, nullptr, XIb,
                                                    NTOK, DM, DI, DM, 2);
    // K7b + K8: init out, then accumulate head
    out_init<<<1, 64, 0, stream>>>(out, cls_b);
    final_kernel<<<NTOK, 256, 0, stream>>>(XIf, XIb, Hb, blk_g, blk_b, cls_w, out);
}

// Round 4
// 799.715 us; speedup vs baseline: 1.8271x; 1.4436x over previous
//
#include <hip/hip_runtime.h>
#include <cstdint>
#include <cstddef>

// ---------------- problem constants ----------------
constexpr int B_   = 16;
constexpr int L_   = 1024;
constexpr int E_   = 192;
constexpr int DM   = 196;   // D_MODEL
constexpr int DI   = 392;   // D_INNER
constexpr int DS   = 16;    // D_STATE
constexpr int DTR  = 13;    // DT_RANK
constexpr int NTOK = B_ * L_;            // 16384
constexpr int XDW  = DTR + 2 * DS;       // 45
constexpr int CH   = B_ * DI;            // 6272 chains per direction

constexpr int KP_XZ = 224;   // 196 padded to %32
constexpr int KP_OP = 416;   // 392 padded to %32
constexpr int KP_PW = 192;

constexpr size_t HW_SZ = (size_t)NTOK * DM;   // 3,211,264
constexpr size_t DI_SZ = (size_t)NTOK * DI;   // 6,422,528

// ---------------- workspace layout (float offsets, all 16B aligned) ----------------
constexpr size_t O_H     = 0;           // h fp32 (NTOK x 196)                 3,211,264
constexpr size_t O_H16   = 3211264;     // h f16 (NTOK x 224)                  1,835,008
constexpr size_t O_XI_F  = 5046272;     // xiT f32 -> dlT f32 -> fo f32        6,422,528
constexpr size_t O_XI_B  = 11468800;    //                                     6,422,528
constexpr size_t O_Z_F   = 17891328;    // zT f32; later ysT16 tok-major f16   6,422,528
constexpr size_t O_Z_B   = 24313856;    //                                     6,422,528
constexpr size_t O_XC_F  = 30736384;    // xcT f32                             6,422,528
constexpr size_t O_XC_B  = 37158912;    //                                     6,422,528
constexpr size_t O_DTR_F = 43581440;    // dt f32 (NTOK x 13)                    212,992
constexpr size_t O_DTR_B = 43794432;
constexpr size_t O_BC_F  = 44007424;    // [B|C] f32 (NTOK x 32)                 524,288
constexpr size_t O_BC_B  = 44531712;
constexpr size_t O_YS_F  = 45056000;    // early Xp f16; later y16 chain-major 3,211,264
constexpr size_t O_YS_B  = 48267264;    // early tok_raw f32; later y16        3,211,264
constexpr size_t O_PW16  = 51478528;    // patch_w f16 192x192                    18,432
constexpr size_t O_FIN16 = 51496960;    // f_in_w f16 784x224                     87,808
constexpr size_t O_BIN16 = 51584768;    // b_in_w f16 784x224                     87,808
constexpr size_t O_FOUT16= 51672576;    // f_out_w f16 196x416                    40,768
constexpr size_t O_BOUT16= 51713344;    // b_out_w f16 196x416   -> end 51,754,112 (~198 MiB)

typedef _Float16 half8 __attribute__((ext_vector_type(8)));
typedef float f32x4v __attribute__((ext_vector_type(4)));

// ---------------- helpers ----------------
__device__ __forceinline__ float siluf(float x) {
    return x / (1.f + __expf(-x));
}

__device__ __forceinline__ float blk_sum(float v, float* red) {
    #pragma unroll
    for (int o = 32; o > 0; o >>= 1) v += __shfl_down(v, o);
    int w = threadIdx.x >> 6;
    __syncthreads();
    if ((threadIdx.x & 63) == 0) red[w] = v;
    __syncthreads();
    return red[0] + red[1] + red[2] + red[3];
}

// ---------------- cvt: f32 (N,K) -> f16 (N,Kpad), zero pad ----------------
__global__ __launch_bounds__(256) void cvt_f16(const float* __restrict__ src,
                                               _Float16* __restrict__ dst,
                                               int N, int K, int Kpad) {
    int i = blockIdx.x * 256 + threadIdx.x;
    if (i >= N * Kpad) return;
    int n = i / Kpad, k = i - n * Kpad;
    dst[i] = (_Float16)(k < K ? src[(size_t)n * K + k] : 0.f);
}

// ---------------- K0: gather patches into (NTOK, 192) f16 ----------------
__global__ __launch_bounds__(256) void gather_patch(const float* __restrict__ x,
                                                    _Float16* __restrict__ Xp) {
    int i = blockIdx.x * 256 + threadIdx.x;
    int tok = i / 192, r = i - tok * 192;
    int c = r >> 6, pq = r & 63, p = pq >> 3, q = pq & 7;
    int b = tok >> 10, l = tok & 1023, hh = l >> 5, wv = l & 31;
    Xp[i] = (_Float16)x[(((size_t)(b * 3 + c) * 256 + hh * 8 + p) << 8) + wv * 8 + q];
}

// ---------------- f16 MFMA GEMM: C(M,N) = A(M,Kpad) @ W(N,Kpad)^T ----------------
// block 256 = 4 waves; block tile 128(m) x 64(n); wave tile 32 x 64.
// A tok-major f16 rows (16B-aligned); optional per-1024 row flip.
// mode 0: C fp32 tok-major (ldc), +bias.  mode 1: C fp32 chain-major [(b*N+n)<<10 | t].
__global__ __launch_bounds__(256) void mfma_gemm(const _Float16* __restrict__ A,
                                                 const _Float16* __restrict__ W,
                                                 const float* __restrict__ bias,
                                                 float* __restrict__ C,
                                                 int N, int Kpad, int ldc,
                                                 int mode, int flip) {
    const int tid = threadIdx.x;
    const int wv = tid >> 6, lane = tid & 63;
    const int col = lane & 15, quad = lane >> 4;
    const int m_base = blockIdx.x * 128 + wv * 32;
    const int n_base = blockIdx.y * 64;

    int r0 = m_base + col, r1 = m_base + 16 + col;
    if (flip) {
        r0 = (r0 & ~1023) + (1023 - (r0 & 1023));
        r1 = (r1 & ~1023) + (1023 - (r1 & 1023));
    }
    const _Float16* a0p = A + (size_t)r0 * Kpad + quad * 8;
    const _Float16* a1p = A + (size_t)r1 * Kpad + quad * 8;

    const _Float16* bp[4];
    bool bok[4];
    #pragma unroll
    for (int j = 0; j < 4; ++j) {
        int n = n_base + j * 16 + col;
        bok[j] = (n < N);
        bp[j] = W + (size_t)(bok[j] ? n : 0) * Kpad + quad * 8;
    }

    f32x4v acc[2][4];
    #pragma unroll
    for (int i = 0; i < 2; ++i)
        #pragma unroll
        for (int j = 0; j < 4; ++j)
            #pragma unroll
            for (int r = 0; r < 4; ++r) acc[i][j][r] = 0.f;

    half8 bzero;
    #pragma unroll
    for (int q = 0; q < 8; ++q) bzero[q] = (_Float16)0.f;

    for (int k0 = 0; k0 < Kpad; k0 += 32) {
        half8 a0 = *(const half8*)(a0p + k0);
        half8 a1 = *(const half8*)(a1p + k0);
        #pragma unroll
        for (int j = 0; j < 4; ++j) {
            half8 bv = bzero;
            if (bok[j]) bv = *(const half8*)(bp[j] + k0);
            acc[0][j] = __builtin_amdgcn_mfma_f32_16x16x32_f16(a0, bv, acc[0][j], 0, 0, 0);
            acc[1][j] = __builtin_amdgcn_mfma_f32_16x16x32_f16(a1, bv, acc[1][j], 0, 0, 0);
        }
    }

    if (mode == 0) {
        #pragma unroll
        for (int i = 0; i < 2; ++i) {
            int mrow = m_base + i * 16 + quad * 4;
            #pragma unroll
            for (int j = 0; j < 4; ++j) {
                int n = n_base + j * 16 + col;
                if (n < N) {
                    float bv = bias ? bias[n] : 0.f;
                    #pragma unroll
                    for (int r = 0; r < 4; ++r)
                        C[(size_t)(mrow + r) * ldc + n] = acc[i][j][r] + bv;
                }
            }
        }
    } else {
        const int bb = m_base >> 10;
        const int t0 = m_base & 1023;
        #pragma unroll
        for (int i = 0; i < 2; ++i) {
            int tt = t0 + i * 16 + quad * 4;
            #pragma unroll
            for (int j = 0; j < 4; ++j) {
                int n = n_base + j * 16 + col;
                if (n < N) {
                    float4 v = {acc[i][j][0], acc[i][j][1], acc[i][j][2], acc[i][j][3]};
                    *(float4*)(C + (((size_t)(bb * N + n)) << 10) + tt) = v;
                }
            }
        }
    }
}

// ---------------- K1b: LN + SiLU + pos -> h fp32 + h f16 (padded 224) ----------------
__global__ __launch_bounds__(256) void ln_silu_pos(const float* __restrict__ tok,
                                                   const float* __restrict__ g,
                                                   const float* __restrict__ bb,
                                                   float* __restrict__ h,
                                                   _Float16* __restrict__ h16) {
    __shared__ float red[4];
    const int t = blockIdx.x;
    const int e = threadIdx.x;
    float v = (e < E_) ? tok[(size_t)t * E_ + e] : 0.f;
    float s1 = blk_sum(v, red);
    float s2 = blk_sum(v * v, red);
    float mean = s1 * (1.f / E_);
    float var = s2 * (1.f / E_) - mean * mean;
    float inv = rsqrtf(var + 1e-5f);
    float hv = 0.f;
    if (e < E_) {
        float o = (v - mean) * inv * g[e] + bb[e];
        hv = siluf(o);
    } else if (e < DM) {
        const int l = t & 1023;
        const float scale = 0.19634954084936207f;  // 2*pi/32
        if (e == E_)          hv = sinf(l * scale);
        else if (e == E_ + 1) hv = cosf(l * scale);
        else if (e == E_ + 2) hv = sinf((float)(l >> 5) * scale);
        else                  hv = cosf((float)(l >> 5) * scale);
    }
    if (e < DM) {
        h[(size_t)t * DM + e] = hv;
        h16[(size_t)t * KP_XZ + e] = (_Float16)hv;
    } else if (e < KP_XZ) {
        h16[(size_t)t * KP_XZ + e] = (_Float16)0.f;
    }
}

// ---------------- K3: depthwise causal conv(4)+SiLU chain-major ----------------
__global__ __launch_bounds__(256) void conv_silu_T(
        const float* __restrict__ xiT_f, const float* __restrict__ xiT_b,
        float* __restrict__ xcT_f, float* __restrict__ xcT_b,
        const float* __restrict__ fw, const float* __restrict__ fb,
        const float* __restrict__ bw, const float* __restrict__ bb2) {
    int i = blockIdx.x * 256 + threadIdx.x;        // < 2*CH*256
    int rall = i >> 8;
    int dir = rall >= CH;
    int r = rall - (dir ? CH : 0);
    int d = r % DI;
    int t0 = (i & 255) << 2;
    const float* xi = (dir ? xiT_b : xiT_f) + ((size_t)r << 10) + t0;
    float cur[4], prev[4] = {0.f, 0.f, 0.f, 0.f};
    *(float4*)cur = *(const float4*)xi;
    if (t0) *(float4*)prev = *(const float4*)(xi - 4);
    const float* w = (dir ? bw : fw) + d * 4;
    float bias = (dir ? bb2 : fb)[d];
    float xv[7] = {prev[1], prev[2], prev[3], cur[0], cur[1], cur[2], cur[3]};
    float o[4];
    #pragma unroll
    for (int tt = 0; tt < 4; ++tt) {
        float a = bias;
        #pragma unroll
        for (int k = 0; k < 4; ++k) a = fmaf(xv[tt + k], w[k], a);
        o[tt] = siluf(a);
    }
    *(float4*)((dir ? xcT_b : xcT_f) + ((size_t)r << 10) + t0) = *(float4*)o;
}

// ---------------- K2b: x_dbl GEMM (fp32): A chain-major, split store dt / [B|C] ----------------
__global__ __launch_bounds__(256) void gemm_xdbl(const float* __restrict__ A,
                                                 const float* __restrict__ W,
                                                 float* __restrict__ dtr,
                                                 float* __restrict__ bc) {
    __shared__ __align__(16) float As[16][68];
    __shared__ __align__(16) float Ws[16][68];
    const int m0 = blockIdx.x * 64;
    const int t = threadIdx.x;
    const int tx = t & 15, ty = t >> 4;
    float acc[4][4] = {};
    const int arow_l = t >> 2;
    const int kq = (t & 3) * 4;
    const int bb_ = m0 >> 10, tt0 = m0 & 1023;
    for (int kt = 0; kt < 25; ++kt) {              // K=392: 24*16+8
        const int k0 = kt << 4;
        {
            int kr = t >> 4, tc = t & 15;
            int kk = k0 + kr;
            float4 v = {0.f, 0.f, 0.f, 0.f};
            if (kk < DI)
                v = *(const float4*)(A + (((size_t)bb_ * DI + kk) << 10) + tt0 + tc * 4);
            *(float4*)&As[kr][tc * 4] = v;
        }
        {
            bool okn = arow_l < XDW;
            const float* wp = W + (size_t)arow_l * DI;
            #pragma unroll
            for (int jj = 0; jj < 4; ++jj) {
                int kk = k0 + kq + jj;
                Ws[kq + jj][arow_l] = (okn && kk < DI) ? wp[kk] : 0.f;
            }
        }
        __syncthreads();
        #pragma unroll
        for (int k = 0; k < 16; ++k) {
            float av[4], wv[4];
            *(float4*)av = *(const float4*)&As[k][ty * 4];
            *(float4*)wv = *(const float4*)&Ws[k][tx * 4];
            #pragma unroll
            for (int i = 0; i < 4; ++i)
                #pragma unroll
                for (int j = 0; j < 4; ++j)
                    acc[i][j] = fmaf(av[i], wv[j], acc[i][j]);
        }
        __syncthreads();
    }
    #pragma unroll
    for (int i = 0; i < 4; ++i) {
        int m = m0 + ty * 4 + i;
        #pragma unroll
        for (int j = 0; j < 4; ++j) {
            int n = tx * 4 + j;
            float v = acc[i][j];
            if (n < DTR) dtr[(size_t)m * DTR + n] = v;
            else if (n < XDW) bc[(size_t)m * 32 + (n - DTR)] = v;
        }
    }
}

// ---------------- K4: delta = softplus(dt @ dt_w^T + dt_b) -> chain-major ----------------
__global__ __launch_bounds__(256) void delta_kernel(
        const float* __restrict__ dtr_f, const float* __restrict__ dtr_b,
        float* __restrict__ dlT_f, float* __restrict__ dlT_b,
        const float* __restrict__ f_dt_w, const float* __restrict__ f_dt_b,
        const float* __restrict__ b_dt_w, const float* __restrict__ b_dt_b) {
    int i = blockIdx.x * 256 + threadIdx.x;       // < 2*DI_SZ
    int dir = i >= (int)DI_SZ;
    int j = dir ? i - (int)DI_SZ : i;             // r*1024 + t
    int r = j >> 10, t = j & 1023;
    int b = r / DI, d = r - (r / DI) * DI;
    size_t tok = ((size_t)b << 10) + t;
    const float* xd = (dir ? dtr_b : dtr_f) + tok * DTR;
    const float* w = (dir ? b_dt_w : f_dt_w) + d * DTR;
    float acc = (dir ? b_dt_b : f_dt_b)[d];
    #pragma unroll
    for (int q = 0; q < DTR; ++q) acc = fmaf(xd[q], w[q], acc);
    float sp = fmaxf(acc, 0.f) + log1pf(__expf(-fabsf(acc)));
    (dir ? dlT_b : dlT_f)[j] = sp;
}

// ---------------- K5: chunked scan, 4 lanes/chain x 4 states, fused gate, f16 out ----------------
// block 256 = 8 chains x 8 chunks x 4 ni
__global__ __launch_bounds__(256) void scan_kernel(
        const float* __restrict__ dlT_f, const float* __restrict__ dlT_b,
        const float* __restrict__ xcT_f, const float* __restrict__ xcT_b,
        const float* __restrict__ bc_f,  const float* __restrict__ bc_b,
        const float* __restrict__ zT_f,  const float* __restrict__ zT_b,
        _Float16* __restrict__ y16_f,    _Float16* __restrict__ y16_b,
        const float* __restrict__ fA, const float* __restrict__ bA,
        const float* __restrict__ fD, const float* __restrict__ bD) {
    __shared__ float sP[8][8][16];
    __shared__ float sH[8][8][16];
    __shared__ float sI[8][8][16];
    const int tid = threadIdx.x;
    const int ni = tid & 3;
    const int c  = (tid >> 2) & 7;
    const int ch_l = tid >> 5;
    const int chain = blockIdx.x * 8 + ch_l;
    const int dir = chain >= CH;
    const int r = chain - (dir ? CH : 0);
    const int b = r / DI, d = r - (r / DI) * DI;

    const float* dlT = (dir ? dlT_b : dlT_f) + ((size_t)r << 10);
    const float* uT  = (dir ? xcT_b : xcT_f) + ((size_t)r << 10);
    const float* zT  = (dir ? zT_b  : zT_f)  + ((size_t)r << 10);
    const float* BC  = (dir ? bc_b  : bc_f)  + (((size_t)b << 10) * 32);
    _Float16* y16    = (dir ? y16_b : y16_f) + ((size_t)r << 10);
    const float* Al  = (dir ? bA : fA) + d * DS + ni * 4;
    float Av[4];
    #pragma unroll
    for (int i = 0; i < 4; ++i) Av[i] = -__expf(Al[i]);
    const float Dd = (dir ? bD : fD)[d];
    const int t0 = c << 7;

    // ---- phase A ----
    if (c < 7) {
        float h[4] = {0.f, 0.f, 0.f, 0.f};
        float S = 0.f;
        for (int g = 0; g < 32; ++g) {
            const int tg = t0 + g * 4;
            float4 d4 = *(const float4*)(dlT + tg);
            float4 u4 = *(const float4*)(uT + tg);
            float dv[4] = {d4.x, d4.y, d4.z, d4.w};
            float uv[4] = {u4.x, u4.y, u4.z, u4.w};
            #pragma unroll
            for (int tt = 0; tt < 4; ++tt) {
                float4 B4 = *(const float4*)(BC + (size_t)(tg + tt) * 32 + ni * 4);
                float w = dv[tt] * uv[tt];
                S += dv[tt];
                float Bv[4] = {B4.x, B4.y, B4.z, B4.w};
                #pragma unroll
                for (int i = 0; i < 4; ++i)
                    h[i] = fmaf(__expf(dv[tt] * Av[i]), h[i], w * Bv[i]);
            }
        }
        #pragma unroll
        for (int i = 0; i < 4; ++i) {
            sP[ch_l][c][ni * 4 + i] = __expf(S * Av[i]);
            sH[ch_l][c][ni * 4 + i] = h[i];
        }
    }
    __syncthreads();

    // ---- phase B ----
    if (tid < 128) {
        const int ch = tid >> 4, n = tid & 15;
        float hi = 0.f;
        #pragma unroll
        for (int cc = 0; cc < 8; ++cc) {
            sI[ch][cc][n] = hi;
            if (cc < 7) hi = sH[ch][cc][n] + sP[ch][cc][n] * hi;
        }
    }
    __syncthreads();

    // ---- phase C ----
    {
        float h[4];
        #pragma unroll
        for (int i = 0; i < 4; ++i) h[i] = sI[ch_l][c][ni * 4 + i];
        for (int g = 0; g < 32; ++g) {
            const int tg = t0 + g * 4;
            float4 d4 = *(const float4*)(dlT + tg);
            float4 u4 = *(const float4*)(uT + tg);
            float4 z4 = *(const float4*)(zT + tg);
            float dv[4] = {d4.x, d4.y, d4.z, d4.w};
            float uv[4] = {u4.x, u4.y, u4.z, u4.w};
            float zv[4] = {z4.x, z4.y, z4.z, z4.w};
            float pq[4];
            #pragma unroll
            for (int tt = 0; tt < 4; ++tt) {
                float4 B4 = *(const float4*)(BC + (size_t)(tg + tt) * 32 + ni * 4);
                float4 C4 = *(const float4*)(BC + (size_t)(tg + tt) * 32 + 16 + ni * 4);
                float w = dv[tt] * uv[tt];
                float Bv[4] = {B4.x, B4.y, B4.z, B4.w};
                float Cv[4] = {C4.x, C4.y, C4.z, C4.w};
                float p = 0.f;
                #pragma unroll
                for (int i = 0; i < 4; ++i) {
                    h[i] = fmaf(__expf(dv[tt] * Av[i]), h[i], w * Bv[i]);
                    p = fmaf(h[i], Cv[i], p);
                }
                pq[tt] = p;
            }
            #pragma unroll
            for (int tt = 0; tt < 4; ++tt) {
                pq[tt] += __shfl_xor(pq[tt], 1);
                pq[tt] += __shfl_xor(pq[tt], 2);
            }
            float ps = (ni == 0) ? pq[0] : (ni == 1) ? pq[1] : (ni == 2) ? pq[2] : pq[3];
            float us = (ni == 0) ? uv[0] : (ni == 1) ? uv[1] : (ni == 2) ? uv[2] : uv[3];
            float zs = (ni == 0) ? zv[0] : (ni == 1) ? zv[1] : (ni == 2) ? zv[2] : zv[3];
            y16[tg + ni] = (_Float16)((ps + Dd * us) * siluf(zs));
        }
    }
}

// ---------------- K5b: transpose y16 chain-major -> tok-major f16 padded 416 ----------------
__global__ __launch_bounds__(256) void transp_y(
        const _Float16* __restrict__ yf, const _Float16* __restrict__ yb,
        _Float16* __restrict__ of, _Float16* __restrict__ ob) {
    __shared__ _Float16 tile[64][72];
    const int dblk = blockIdx.z % 7, dir = blockIdx.z / 7;
    const int b = blockIdx.y, tb = blockIdx.x;
    const _Float16* y = dir ? yb : yf;
    _Float16* o = dir ? ob : of;
    const int d0 = dblk * 64, t0 = tb * 64;
    const int dl = threadIdx.x >> 2, ts = (threadIdx.x & 3) * 16;
    const int d = d0 + dl;
    if (d < DI) {
        const _Float16* src = y + (((size_t)(b * DI + d)) << 10) + t0 + ts;
        *(half8*)&tile[dl][ts] = *(const half8*)src;
        *(half8*)&tile[dl][ts + 8] = *(const half8*)(src + 8);
    } else {
        #pragma unroll
        for (int q = 0; q < 16; ++q) tile[dl][ts + q] = (_Float16)0.f;
    }
    __syncthreads();
    const int tl = threadIdx.x >> 2, ds = (threadIdx.x & 3) * 16;
    if (d0 + ds < KP_OP) {
        _Float16 v[16] __attribute__((aligned(16)));
        #pragma unroll
        for (int q = 0; q < 16; ++q) v[q] = tile[ds + q][tl];
        _Float16* dst = o + ((size_t)((b << 10) + t0 + tl)) * KP_OP + d0 + ds;
        *(half8*)dst = *(half8*)&v[0];
        *(half8*)(dst + 8) = *(half8*)&v[8];
    }
}

// ---------------- K7b: init d_out ----------------
__global__ void out_init(float* __restrict__ out, const float* __restrict__ cls_b) {
    if (threadIdx.x < B_) out[threadIdx.x] = cls_b[0];
}

// ---------------- K8: combine, LN, SiLU, residual, cls head ----------------
__global__ __launch_bounds__(256) void final_kernel(
        const float* __restrict__ fo, const float* __restrict__ bo,
        const float* __restrict__ h, const float* __restrict__ g,
        const float* __restrict__ bb, const float* __restrict__ cls_w,
        float* __restrict__ out) {
    __shared__ float red[4];
    const int t = blockIdx.x;
    const int b = t >> 10, l = t & 1023;
    const int e = threadIdx.x;
    float v = 0.f;
    if (e < DM)
        v = 0.5f * (fo[(size_t)t * DM + e] + bo[((size_t)b * L_ + (L_ - 1 - l)) * DM + e]);
    float s1 = blk_sum(v, red);
    float s2 = blk_sum(v * v, red);
    float mean = s1 * (1.f / DM);
    float var = s2 * (1.f / DM) - mean * mean;
    float inv = rsqrtf(var + 1e-5f);
    float c = 0.f;
    if (e < DM) {
        float o = (v - mean) * inv * g[e] + bb[e];
        o = siluf(o) + h[(size_t)t * DM + e];
        c = o * cls_w[e];
    }
    float s = blk_sum(c, red);
    if (e == 0) atomicAdd(&out[b], s * (1.f / 1024.f));
}

// ---------------- launch ----------------
extern "C" void kernel_launch(void* const* d_in, const int* in_sizes, int n_in,
                              void* d_out, int out_size, void* d_ws, size_t ws_size,
                              hipStream_t stream) {
    const float* x        = (const float*)d_in[0];
    const float* patch_w  = (const float*)d_in[1];
    const float* patch_b  = (const float*)d_in[2];
    const float* pe_g     = (const float*)d_in[3];
    const float* pe_b     = (const float*)d_in[4];
    const float* blk_g    = (const float*)d_in[5];
    const float* blk_b    = (const float*)d_in[6];
    const float* cls_w    = (const float*)d_in[7];
    const float* cls_b    = (const float*)d_in[8];
    const float* f_in_w   = (const float*)d_in[9];
    const float* f_conv_w = (const float*)d_in[10];
    const float* f_conv_b = (const float*)d_in[11];
    const float* f_xp_w   = (const float*)d_in[12];
    const float* f_dt_w   = (const float*)d_in[13];
    const float* f_dt_b   = (const float*)d_in[14];
    const float* f_A_log  = (const float*)d_in[15];
    const float* f_D      = (const float*)d_in[16];
    const float* f_out_w  = (const float*)d_in[17];
    const float* b_in_w   = (const float*)d_in[18];
    const float* b_conv_w = (const float*)d_in[19];
    const float* b_conv_b = (const float*)d_in[20];
    const float* b_xp_w   = (const float*)d_in[21];
    const float* b_dt_w   = (const float*)d_in[22];
    const float* b_dt_b   = (const float*)d_in[23];
    const float* b_A_log  = (const float*)d_in[24];
    const float* b_D      = (const float*)d_in[25];
    const float* b_out_w  = (const float*)d_in[26];

    float* ws = (float*)d_ws;
    float* out = (float*)d_out;

    float* Hb        = ws + O_H;
    _Float16* H16    = (_Float16*)(ws + O_H16);
    float* XIf       = ws + O_XI_F;
    float* XIb       = ws + O_XI_B;
    float* Zf        = ws + O_Z_F;
    float* Zb        = ws + O_Z_B;
    _Float16* YsTf16 = (_Float16*)(ws + O_Z_F);   // after scan: tok-major ys f16
    _Float16* YsTb16 = (_Float16*)(ws + O_Z_B);
    float* XCf       = ws + O_XC_F;
    float* XCb       = ws + O_XC_B;
    float* DTRf      = ws + O_DTR_F;
    float* DTRb      = ws + O_DTR_B;
    float* BCf       = ws + O_BC_F;
    float* BCb       = ws + O_BC_B;
    _Float16* Xp16   = (_Float16*)(ws + O_YS_F);  // early
    float* TokRaw    = ws + O_YS_B;               // early
    _Float16* Y16f   = (_Float16*)(ws + O_YS_F);  // after scan
    _Float16* Y16b   = (_Float16*)(ws + O_YS_B);
    _Float16* PW16   = (_Float16*)(ws + O_PW16);
    _Float16* FIN16  = (_Float16*)(ws + O_FIN16);
    _Float16* BIN16  = (_Float16*)(ws + O_BIN16);
    _Float16* FOUT16 = (_Float16*)(ws + O_FOUT16);
    _Float16* BOUT16 = (_Float16*)(ws + O_BOUT16);

    // weight conversions
    cvt_f16<<<(192 * KP_PW + 255) / 256, 256, 0, stream>>>(patch_w, PW16, 192, 192, KP_PW);
    cvt_f16<<<(784 * KP_XZ + 255) / 256, 256, 0, stream>>>(f_in_w, FIN16, 784, DM, KP_XZ);
    cvt_f16<<<(784 * KP_XZ + 255) / 256, 256, 0, stream>>>(b_in_w, BIN16, 784, DM, KP_XZ);
    cvt_f16<<<(DM * KP_OP + 255) / 256, 256, 0, stream>>>(f_out_w, FOUT16, DM, DI, KP_OP);
    cvt_f16<<<(DM * KP_OP + 255) / 256, 256, 0, stream>>>(b_out_w, BOUT16, DM, DI, KP_OP);

    // patch embed
    gather_patch<<<(NTOK * 192) / 256, 256, 0, stream>>>(x, Xp16);
    mfma_gemm<<<dim3(NTOK / 128, 3), 256, 0, stream>>>(Xp16, PW16, patch_b, TokRaw,
                                                       192, KP_PW, 192, 0, 0);
    ln_silu_pos<<<NTOK, 256, 0, stream>>>(TokRaw, pe_g, pe_b, Hb, H16);

    // xz projections -> chain-major fp32
    mfma_gemm<<<dim3(NTOK / 128, 7), 256, 0, stream>>>(H16, FIN16, nullptr, XIf,
                                                       DI, KP_XZ, 0, 1, 0);
    mfma_gemm<<<dim3(NTOK / 128, 7), 256, 0, stream>>>(H16, FIN16 + (size_t)DI * KP_XZ,
                                                       nullptr, Zf, DI, KP_XZ, 0, 1, 0);
    mfma_gemm<<<dim3(NTOK / 128, 7), 256, 0, stream>>>(H16, BIN16, nullptr, XIb,
                                                       DI, KP_XZ, 0, 1, 1);
    mfma_gemm<<<dim3(NTOK / 128, 7), 256, 0, stream>>>(H16, BIN16 + (size_t)DI * KP_XZ,
                                                       nullptr, Zb, DI, KP_XZ, 0, 1, 1);

    // conv + silu
    conv_silu_T<<<2 * CH, 256, 0, stream>>>(XIf, XIb, XCf, XCb,
                                            f_conv_w, f_conv_b, b_conv_w, b_conv_b);
    // x_dbl (fp32) -> dt + [B|C]
    gemm_xdbl<<<NTOK / 64, 256, 0, stream>>>(XCf, f_xp_w, DTRf, BCf);
    gemm_xdbl<<<NTOK / 64, 256, 0, stream>>>(XCb, b_xp_w, DTRb, BCb);
    // delta -> dlT (overwrites dead xiT)
    delta_kernel<<<(2 * (int)DI_SZ) / 256, 256, 0, stream>>>(
        DTRf, DTRb, XIf, XIb, f_dt_w, f_dt_b, b_dt_w, b_dt_b);
    // scan + gate -> y16 chain-major
    scan_kernel<<<2 * CH / 8, 256, 0, stream>>>(
        XIf, XIb, XCf, XCb, BCf, BCb, Zf, Zb, Y16f, Y16b,
        f_A_log, b_A_log, f_D, b_D);
    // transpose -> tok-major f16 (into dead Z regions)
    transp_y<<<dim3(16, 16, 14), 256, 0, stream>>>(Y16f, Y16b, YsTf16, YsTb16);
    // out projections -> fo/bo fp32 tok-major (into dead dlT regions)
    mfma_gemm<<<dim3(NTOK / 128, 4), 256, 0, stream>>>(YsTf16, FOUT16, nullptr, XIf,
                                                       DM, KP_OP, DM, 0, 0);
    mfma_gemm<<<dim3(NTOK / 128, 4), 256, 0, stream>>>(YsTb16, BOUT16, nullptr, XIb,
                                                       DM, KP_OP, DM, 0, 0);
    // head
    out_init<<<1, 64, 0, stream>>>(out, cls_b);
    final_kernel<<<NTOK, 256, 0, stream>>>(XIf, XIb, Hb, blk_g, blk_b, cls_w, out);
}

// Round 5
// 576.203 us; speedup vs baseline: 2.5359x; 1.3879x over previous
//
#include <hip/hip_runtime.h>
#include <cstdint>
#include <cstddef>

// ---------------- problem constants ----------------
constexpr int B_   = 16;
constexpr int L_   = 1024;
constexpr int E_   = 192;
constexpr int DM   = 196;   // D_MODEL
constexpr int DI   = 392;   // D_INNER
constexpr int DS   = 16;    // D_STATE
constexpr int DTR  = 13;    // DT_RANK
constexpr int NTOK = B_ * L_;            // 16384
constexpr int XDW  = DTR + 2 * DS;       // 45
constexpr int CH   = B_ * DI;            // 6272 chains per direction

constexpr int KP_XZ = 224;   // 196 padded to %32
constexpr int KP_OP = 416;   // 392 padded to %32
constexpr int KP_PW = 192;

constexpr size_t HW_SZ = (size_t)NTOK * DM;   // 3,211,264
constexpr size_t DI_SZ = (size_t)NTOK * DI;   // 6,422,528

// ---------------- workspace layout (float offsets, all 16B aligned) ----------------
constexpr size_t O_H     = 0;           // h fp32 (NTOK x 196)                 3,211,264
constexpr size_t O_H16   = 3211264;     // h f16 (NTOK x 224)                  1,835,008
constexpr size_t O_XI_F  = 5046272;     // xiT f32 -> dlT f32 -> fo f32        6,422,528
constexpr size_t O_XI_B  = 11468800;    //                                     6,422,528
constexpr size_t O_Z_F   = 17891328;    // zT f32; later ysT16 tok-major f16   6,422,528
constexpr size_t O_Z_B   = 24313856;    //                                     6,422,528
constexpr size_t O_XC_F  = 30736384;    // xcT f32; later head partials        6,422,528
constexpr size_t O_XC_B  = 37158912;    //                                     6,422,528
constexpr size_t O_DTR_F = 43581440;    // dt f32 (NTOK x 13)                    212,992
constexpr size_t O_DTR_B = 43794432;
constexpr size_t O_BC_F  = 44007424;    // [B|C] f32 (NTOK x 32)                 524,288
constexpr size_t O_BC_B  = 44531712;
constexpr size_t O_YS_F  = 45056000;    // early Xp f16; later y16 chain-major 3,211,264
constexpr size_t O_YS_B  = 48267264;    // early tok_raw f32; later y16        3,211,264
constexpr size_t O_PW16  = 51478528;    // patch_w f16 192x192                    18,432
constexpr size_t O_FIN16 = 51496960;    // f_in_w f16 784x224                     87,808
constexpr size_t O_BIN16 = 51584768;    // b_in_w f16 784x224                     87,808
constexpr size_t O_FOUT16= 51672576;    // f_out_w f16 196x416                    40,768
constexpr size_t O_BOUT16= 51713344;    // b_out_w f16 196x416   -> end 51,754,112 (~198 MiB)

typedef _Float16 half8 __attribute__((ext_vector_type(8)));
typedef float f32x4v __attribute__((ext_vector_type(4)));

// ---------------- helpers ----------------
__device__ __forceinline__ float siluf(float x) {
    return x / (1.f + __expf(-x));
}

__device__ __forceinline__ float blk_sum(float v, float* red) {
    #pragma unroll
    for (int o = 32; o > 0; o >>= 1) v += __shfl_down(v, o);
    int w = threadIdx.x >> 6;
    __syncthreads();
    if ((threadIdx.x & 63) == 0) red[w] = v;
    __syncthreads();
    return red[0] + red[1] + red[2] + red[3];
}

// ---------------- cvt: f32 (N,K) -> f16 (N,Kpad), zero pad ----------------
__global__ __launch_bounds__(256) void cvt_f16(const float* __restrict__ src,
                                               _Float16* __restrict__ dst,
                                               int N, int K, int Kpad) {
    int i = blockIdx.x * 256 + threadIdx.x;
    if (i >= N * Kpad) return;
    int n = i / Kpad, k = i - n * Kpad;
    dst[i] = (_Float16)(k < K ? src[(size_t)n * K + k] : 0.f);
}

// ---------------- K0: gather patches into (NTOK, 192) f16 ----------------
__global__ __launch_bounds__(256) void gather_patch(const float* __restrict__ x,
                                                    _Float16* __restrict__ Xp) {
    int i = blockIdx.x * 256 + threadIdx.x;
    int tok = i / 192, r = i - tok * 192;
    int c = r >> 6, pq = r & 63, p = pq >> 3, q = pq & 7;
    int b = tok >> 10, l = tok & 1023, hh = l >> 5, wv = l & 31;
    Xp[i] = (_Float16)x[(((size_t)(b * 3 + c) * 256 + hh * 8 + p) << 8) + wv * 8 + q];
}

// ---------------- f16 MFMA GEMM: C(M,N) = A(M,Kpad) @ W(N,Kpad)^T ----------------
__global__ __launch_bounds__(256) void mfma_gemm(const _Float16* __restrict__ A,
                                                 const _Float16* __restrict__ W,
                                                 const float* __restrict__ bias,
                                                 float* __restrict__ C,
                                                 int N, int Kpad, int ldc,
                                                 int mode, int flip) {
    const int tid = threadIdx.x;
    const int wv = tid >> 6, lane = tid & 63;
    const int col = lane & 15, quad = lane >> 4;
    const int m_base = blockIdx.x * 128 + wv * 32;
    const int n_base = blockIdx.y * 64;

    int r0 = m_base + col, r1 = m_base + 16 + col;
    if (flip) {
        r0 = (r0 & ~1023) + (1023 - (r0 & 1023));
        r1 = (r1 & ~1023) + (1023 - (r1 & 1023));
    }
    const _Float16* a0p = A + (size_t)r0 * Kpad + quad * 8;
    const _Float16* a1p = A + (size_t)r1 * Kpad + quad * 8;

    const _Float16* bp[4];
    bool bok[4];
    #pragma unroll
    for (int j = 0; j < 4; ++j) {
        int n = n_base + j * 16 + col;
        bok[j] = (n < N);
        bp[j] = W + (size_t)(bok[j] ? n : 0) * Kpad + quad * 8;
    }

    f32x4v acc[2][4];
    #pragma unroll
    for (int i = 0; i < 2; ++i)
        #pragma unroll
        for (int j = 0; j < 4; ++j)
            #pragma unroll
            for (int r = 0; r < 4; ++r) acc[i][j][r] = 0.f;

    half8 bzero;
    #pragma unroll
    for (int q = 0; q < 8; ++q) bzero[q] = (_Float16)0.f;

    for (int k0 = 0; k0 < Kpad; k0 += 32) {
        half8 a0 = *(const half8*)(a0p + k0);
        half8 a1 = *(const half8*)(a1p + k0);
        #pragma unroll
        for (int j = 0; j < 4; ++j) {
            half8 bv = bzero;
            if (bok[j]) bv = *(const half8*)(bp[j] + k0);
            acc[0][j] = __builtin_amdgcn_mfma_f32_16x16x32_f16(a0, bv, acc[0][j], 0, 0, 0);
            acc[1][j] = __builtin_amdgcn_mfma_f32_16x16x32_f16(a1, bv, acc[1][j], 0, 0, 0);
        }
    }

    if (mode == 0) {
        #pragma unroll
        for (int i = 0; i < 2; ++i) {
            int mrow = m_base + i * 16 + quad * 4;
            #pragma unroll
            for (int j = 0; j < 4; ++j) {
                int n = n_base + j * 16 + col;
                if (n < N) {
                    float bv = bias ? bias[n] : 0.f;
                    #pragma unroll
                    for (int r = 0; r < 4; ++r)
                        C[(size_t)(mrow + r) * ldc + n] = acc[i][j][r] + bv;
                }
            }
        }
    } else {
        const int bb = m_base >> 10;
        const int t0 = m_base & 1023;
        #pragma unroll
        for (int i = 0; i < 2; ++i) {
            int tt = t0 + i * 16 + quad * 4;
            #pragma unroll
            for (int j = 0; j < 4; ++j) {
                int n = n_base + j * 16 + col;
                if (n < N) {
                    float4 v = {acc[i][j][0], acc[i][j][1], acc[i][j][2], acc[i][j][3]};
                    *(float4*)(C + (((size_t)(bb * N + n)) << 10) + tt) = v;
                }
            }
        }
    }
}

// ---------------- K1b: LN + SiLU + pos -> h fp32 + h f16; one wave per token ----------------
__global__ __launch_bounds__(256) void ln_silu_pos(const float* __restrict__ tok,
                                                   const float* __restrict__ g,
                                                   const float* __restrict__ bb,
                                                   float* __restrict__ h,
                                                   _Float16* __restrict__ h16) {
    const int w = threadIdx.x >> 6, lane = threadIdx.x & 63;
    const int t = blockIdx.x * 4 + w;
    const float* tp = tok + (size_t)t * E_;
    float v[3];
    float s1 = 0.f, s2 = 0.f;
    #pragma unroll
    for (int i = 0; i < 3; ++i) {
        v[i] = tp[lane + i * 64];
        s1 += v[i];
        s2 = fmaf(v[i], v[i], s2);
    }
    #pragma unroll
    for (int o = 32; o > 0; o >>= 1) {
        s1 += __shfl_xor(s1, o);
        s2 += __shfl_xor(s2, o);
    }
    float mean = s1 * (1.f / E_);
    float var = s2 * (1.f / E_) - mean * mean;
    float inv = rsqrtf(var + 1e-5f);
    float* hp = h + (size_t)t * DM;
    _Float16* hq = h16 + (size_t)t * KP_XZ;
    #pragma unroll
    for (int i = 0; i < 3; ++i) {
        int e = lane + i * 64;
        float o = siluf((v[i] - mean) * inv * g[e] + bb[e]);
        hp[e] = o;
        hq[e] = (_Float16)o;
    }
    const int l = t & 1023;
    const float scale = 0.19634954084936207f;  // 2*pi/32
    if (lane < 4) {
        float pv = (lane == 0) ? sinf(l * scale)
                 : (lane == 1) ? cosf(l * scale)
                 : (lane == 2) ? sinf((float)(l >> 5) * scale)
                 :               cosf((float)(l >> 5) * scale);
        hp[E_ + lane] = pv;
        hq[E_ + lane] = (_Float16)pv;
    } else if (lane < 32) {
        hq[192 + lane] = (_Float16)0.f;   // pad 196..223
    }
}

// ---------------- K3: depthwise causal conv(4)+SiLU chain-major ----------------
__global__ __launch_bounds__(256) void conv_silu_T(
        const float* __restrict__ xiT_f, const float* __restrict__ xiT_b,
        float* __restrict__ xcT_f, float* __restrict__ xcT_b,
        const float* __restrict__ fw, const float* __restrict__ fb,
        const float* __restrict__ bw, const float* __restrict__ bb2) {
    int i = blockIdx.x * 256 + threadIdx.x;        // < 2*CH*256
    int rall = i >> 8;
    int dir = rall >= CH;
    int r = rall - (dir ? CH : 0);
    int d = r % DI;
    int t0 = (i & 255) << 2;
    const float* xi = (dir ? xiT_b : xiT_f) + ((size_t)r << 10) + t0;
    float cur[4], prev[4] = {0.f, 0.f, 0.f, 0.f};
    *(float4*)cur = *(const float4*)xi;
    if (t0) *(float4*)prev = *(const float4*)(xi - 4);
    const float* w = (dir ? bw : fw) + d * 4;
    float bias = (dir ? bb2 : fb)[d];
    float xv[7] = {prev[1], prev[2], prev[3], cur[0], cur[1], cur[2], cur[3]};
    float o[4];
    #pragma unroll
    for (int tt = 0; tt < 4; ++tt) {
        float a = bias;
        #pragma unroll
        for (int k = 0; k < 4; ++k) a = fmaf(xv[tt + k], w[k], a);
        o[tt] = siluf(a);
    }
    *(float4*)((dir ? xcT_b : xcT_f) + ((size_t)r << 10) + t0) = *(float4*)o;
}

// ---------------- K2b: x_dbl GEMM (fp32): A chain-major, split store dt / [B|C] ----------------
__global__ __launch_bounds__(256) void gemm_xdbl(const float* __restrict__ A,
                                                 const float* __restrict__ W,
                                                 float* __restrict__ dtr,
                                                 float* __restrict__ bc) {
    __shared__ __align__(16) float As[16][68];
    __shared__ __align__(16) float Ws[16][68];
    const int m0 = blockIdx.x * 64;
    const int t = threadIdx.x;
    const int tx = t & 15, ty = t >> 4;
    float acc[4][4] = {};
    const int arow_l = t >> 2;
    const int kq = (t & 3) * 4;
    const int bb_ = m0 >> 10, tt0 = m0 & 1023;
    for (int kt = 0; kt < 25; ++kt) {              // K=392: 24*16+8
        const int k0 = kt << 4;
        {
            int kr = t >> 4, tc = t & 15;
            int kk = k0 + kr;
            float4 v = {0.f, 0.f, 0.f, 0.f};
            if (kk < DI)
                v = *(const float4*)(A + (((size_t)bb_ * DI + kk) << 10) + tt0 + tc * 4);
            *(float4*)&As[kr][tc * 4] = v;
        }
        {
            bool okn = arow_l < XDW;
            const float* wp = W + (size_t)arow_l * DI;
            #pragma unroll
            for (int jj = 0; jj < 4; ++jj) {
                int kk = k0 + kq + jj;
                Ws[kq + jj][arow_l] = (okn && kk < DI) ? wp[kk] : 0.f;
            }
        }
        __syncthreads();
        #pragma unroll
        for (int k = 0; k < 16; ++k) {
            float av[4], wv[4];
            *(float4*)av = *(const float4*)&As[k][ty * 4];
            *(float4*)wv = *(const float4*)&Ws[k][tx * 4];
            #pragma unroll
            for (int i = 0; i < 4; ++i)
                #pragma unroll
                for (int j = 0; j < 4; ++j)
                    acc[i][j] = fmaf(av[i], wv[j], acc[i][j]);
        }
        __syncthreads();
    }
    #pragma unroll
    for (int i = 0; i < 4; ++i) {
        int m = m0 + ty * 4 + i;
        #pragma unroll
        for (int j = 0; j < 4; ++j) {
            int n = tx * 4 + j;
            float v = acc[i][j];
            if (n < DTR) dtr[(size_t)m * DTR + n] = v;
            else if (n < XDW) bc[(size_t)m * 32 + (n - DTR)] = v;
        }
    }
}

// ---------------- K4: delta = softplus(dt @ dt_w^T + dt_b) -> chain-major ----------------
__global__ __launch_bounds__(256) void delta_kernel(
        const float* __restrict__ dtr_f, const float* __restrict__ dtr_b,
        float* __restrict__ dlT_f, float* __restrict__ dlT_b,
        const float* __restrict__ f_dt_w, const float* __restrict__ f_dt_b,
        const float* __restrict__ b_dt_w, const float* __restrict__ b_dt_b) {
    int i = blockIdx.x * 256 + threadIdx.x;       // < 2*DI_SZ
    int dir = i >= (int)DI_SZ;
    int j = dir ? i - (int)DI_SZ : i;             // r*1024 + t
    int r = j >> 10, t = j & 1023;
    int b = r / DI, d = r - (r / DI) * DI;
    size_t tok = ((size_t)b << 10) + t;
    const float* xd = (dir ? dtr_b : dtr_f) + tok * DTR;
    const float* w = (dir ? b_dt_w : f_dt_w) + d * DTR;
    float acc = (dir ? b_dt_b : f_dt_b)[d];
    #pragma unroll
    for (int q = 0; q < DTR; ++q) acc = fmaf(xd[q], w[q], acc);
    float sp = fmaxf(acc, 0.f) + log1pf(__expf(-fabsf(acc)));
    (dir ? dlT_b : dlT_f)[j] = sp;
}

// ---------------- K5: chunked scan, 4 lanes/chain x 4 states, fused gate, f16 out ----------------
__global__ __launch_bounds__(256) void scan_kernel(
        const float* __restrict__ dlT_f, const float* __restrict__ dlT_b,
        const float* __restrict__ xcT_f, const float* __restrict__ xcT_b,
        const float* __restrict__ bc_f,  const float* __restrict__ bc_b,
        const float* __restrict__ zT_f,  const float* __restrict__ zT_b,
        _Float16* __restrict__ y16_f,    _Float16* __restrict__ y16_b,
        const float* __restrict__ fA, const float* __restrict__ bA,
        const float* __restrict__ fD, const float* __restrict__ bD) {
    __shared__ float sP[8][8][16];
    __shared__ float sH[8][8][16];
    __shared__ float sI[8][8][16];
    const int tid = threadIdx.x;
    const int ni = tid & 3;
    const int c  = (tid >> 2) & 7;
    const int ch_l = tid >> 5;
    const int chain = blockIdx.x * 8 + ch_l;
    const int dir = chain >= CH;
    const int r = chain - (dir ? CH : 0);
    const int b = r / DI, d = r - (r / DI) * DI;

    const float* dlT = (dir ? dlT_b : dlT_f) + ((size_t)r << 10);
    const float* uT  = (dir ? xcT_b : xcT_f) + ((size_t)r << 10);
    const float* zT  = (dir ? zT_b  : zT_f)  + ((size_t)r << 10);
    const float* BC  = (dir ? bc_b  : bc_f)  + (((size_t)b << 10) * 32);
    _Float16* y16    = (dir ? y16_b : y16_f) + ((size_t)r << 10);
    const float* Al  = (dir ? bA : fA) + d * DS + ni * 4;
    float Av[4];
    #pragma unroll
    for (int i = 0; i < 4; ++i) Av[i] = -__expf(Al[i]);
    const float Dd = (dir ? bD : fD)[d];
    const int t0 = c << 7;

    // ---- phase A ----
    if (c < 7) {
        float h[4] = {0.f, 0.f, 0.f, 0.f};
        float S = 0.f;
        for (int g = 0; g < 32; ++g) {
            const int tg = t0 + g * 4;
            float4 d4 = *(const float4*)(dlT + tg);
            float4 u4 = *(const float4*)(uT + tg);
            float dv[4] = {d4.x, d4.y, d4.z, d4.w};
            float uv[4] = {u4.x, u4.y, u4.z, u4.w};
            #pragma unroll
            for (int tt = 0; tt < 4; ++tt) {
                float4 B4 = *(const float4*)(BC + (size_t)(tg + tt) * 32 + ni * 4);
                float w = dv[tt] * uv[tt];
                S += dv[tt];
                float Bv[4] = {B4.x, B4.y, B4.z, B4.w};
                #pragma unroll
                for (int i = 0; i < 4; ++i)
                    h[i] = fmaf(__expf(dv[tt] * Av[i]), h[i], w * Bv[i]);
            }
        }
        #pragma unroll
        for (int i = 0; i < 4; ++i) {
            sP[ch_l][c][ni * 4 + i] = __expf(S * Av[i]);
            sH[ch_l][c][ni * 4 + i] = h[i];
        }
    }
    __syncthreads();

    // ---- phase B ----
    if (tid < 128) {
        const int ch = tid >> 4, n = tid & 15;
        float hi = 0.f;
        #pragma unroll
        for (int cc = 0; cc < 8; ++cc) {
            sI[ch][cc][n] = hi;
            if (cc < 7) hi = sH[ch][cc][n] + sP[ch][cc][n] * hi;
        }
    }
    __syncthreads();

    // ---- phase C ----
    {
        float h[4];
        #pragma unroll
        for (int i = 0; i < 4; ++i) h[i] = sI[ch_l][c][ni * 4 + i];
        for (int g = 0; g < 32; ++g) {
            const int tg = t0 + g * 4;
            float4 d4 = *(const float4*)(dlT + tg);
            float4 u4 = *(const float4*)(uT + tg);
            float4 z4 = *(const float4*)(zT + tg);
            float dv[4] = {d4.x, d4.y, d4.z, d4.w};
            float uv[4] = {u4.x, u4.y, u4.z, u4.w};
            float zv[4] = {z4.x, z4.y, z4.z, z4.w};
            float pq[4];
            #pragma unroll
            for (int tt = 0; tt < 4; ++tt) {
                float4 B4 = *(const float4*)(BC + (size_t)(tg + tt) * 32 + ni * 4);
                float4 C4 = *(const float4*)(BC + (size_t)(tg + tt) * 32 + 16 + ni * 4);
                float w = dv[tt] * uv[tt];
                float Bv[4] = {B4.x, B4.y, B4.z, B4.w};
                float Cv[4] = {C4.x, C4.y, C4.z, C4.w};
                float p = 0.f;
                #pragma unroll
                for (int i = 0; i < 4; ++i) {
                    h[i] = fmaf(__expf(dv[tt] * Av[i]), h[i], w * Bv[i]);
                    p = fmaf(h[i], Cv[i], p);
                }
                pq[tt] = p;
            }
            #pragma unroll
            for (int tt = 0; tt < 4; ++tt) {
                pq[tt] += __shfl_xor(pq[tt], 1);
                pq[tt] += __shfl_xor(pq[tt], 2);
            }
            float ps = (ni == 0) ? pq[0] : (ni == 1) ? pq[1] : (ni == 2) ? pq[2] : pq[3];
            float us = (ni == 0) ? uv[0] : (ni == 1) ? uv[1] : (ni == 2) ? uv[2] : uv[3];
            float zs = (ni == 0) ? zv[0] : (ni == 1) ? zv[1] : (ni == 2) ? zv[2] : zv[3];
            y16[tg + ni] = (_Float16)((ps + Dd * us) * siluf(zs));
        }
    }
}

// ---------------- K5b: transpose y16 chain-major -> tok-major f16 padded 416 ----------------
__global__ __launch_bounds__(256) void transp_y(
        const _Float16* __restrict__ yf, const _Float16* __restrict__ yb,
        _Float16* __restrict__ of, _Float16* __restrict__ ob) {
    __shared__ _Float16 tile[64][72];
    const int dblk = blockIdx.z % 7, dir = blockIdx.z / 7;
    const int b = blockIdx.y, tb = blockIdx.x;
    const _Float16* y = dir ? yb : yf;
    _Float16* o = dir ? ob : of;
    const int d0 = dblk * 64, t0 = tb * 64;
    const int dl = threadIdx.x >> 2, ts = (threadIdx.x & 3) * 16;
    const int d = d0 + dl;
    if (d < DI) {
        const _Float16* src = y + (((size_t)(b * DI + d)) << 10) + t0 + ts;
        *(half8*)&tile[dl][ts] = *(const half8*)src;
        *(half8*)&tile[dl][ts + 8] = *(const half8*)(src + 8);
    } else {
        #pragma unroll
        for (int q = 0; q < 16; ++q) tile[dl][ts + q] = (_Float16)0.f;
    }
    __syncthreads();
    const int tl = threadIdx.x >> 2, ds = (threadIdx.x & 3) * 16;
    if (d0 + ds < KP_OP) {
        _Float16 v[16] __attribute__((aligned(16)));
        #pragma unroll
        for (int q = 0; q < 16; ++q) v[q] = tile[ds + q][tl];
        _Float16* dst = o + ((size_t)((b << 10) + t0 + tl)) * KP_OP + d0 + ds;
        *(half8*)dst = *(half8*)&v[0];
        *(half8*)(dst + 8) = *(half8*)&v[8];
    }
}

// ---------------- K8a: head partials — one wave per token, no atomics ----------------
__global__ __launch_bounds__(256) void final_head(
        const float* __restrict__ fo, const float* __restrict__ bo,
        const float* __restrict__ h, const float* __restrict__ g,
        const float* __restrict__ bb, const float* __restrict__ cls_w,
        float* __restrict__ partial) {
    const int w = threadIdx.x >> 6, lane = threadIdx.x & 63;
    const int t = blockIdx.x * 4 + w;
    const int b = t >> 10, l = t & 1023;
    const float* fp = fo + (size_t)t * DM;
    const float* bp = bo + ((size_t)(b << 10) + (1023 - l)) * DM;
    const float* hp = h + (size_t)t * DM;
    float v[4];
    float s1 = 0.f, s2 = 0.f;
    #pragma unroll
    for (int i = 0; i < 4; ++i) {
        int e = lane + i * 64;
        bool ok = (i < 3) || (lane < 4);
        float vv = ok ? 0.5f * (fp[e] + bp[e]) : 0.f;
        v[i] = vv;
        s1 += vv;
        s2 = fmaf(vv, vv, s2);
    }
    #pragma unroll
    for (int o = 32; o > 0; o >>= 1) {
        s1 += __shfl_xor(s1, o);
        s2 += __shfl_xor(s2, o);
    }
    float mean = s1 * (1.f / DM);
    float var = s2 * (1.f / DM) - mean * mean;
    float inv = rsqrtf(var + 1e-5f);
    float c = 0.f;
    #pragma unroll
    for (int i = 0; i < 4; ++i) {
        int e = lane + i * 64;
        bool ok = (i < 3) || (lane < 4);
        if (ok) {
            float o2 = (v[i] - mean) * inv * g[e] + bb[e];
            o2 = siluf(o2) + hp[e];
            c = fmaf(o2, cls_w[e], c);
        }
    }
    #pragma unroll
    for (int o = 32; o > 0; o >>= 1) c += __shfl_xor(c, o);
    if (lane == 0) partial[t] = c;
}

// ---------------- K8b: reduce 1024 partials per batch -> out ----------------
__global__ __launch_bounds__(256) void head_reduce(const float* __restrict__ partial,
                                                   const float* __restrict__ cls_b,
                                                   float* __restrict__ out) {
    __shared__ float red[4];
    const int b = blockIdx.x;
    const float* p = partial + ((size_t)b << 10);
    float s = 0.f;
    for (int i = threadIdx.x; i < 1024; i += 256) s += p[i];
    s = blk_sum(s, red);
    if (threadIdx.x == 0) out[b] = s * (1.f / 1024.f) + cls_b[0];
}

// ---------------- launch ----------------
extern "C" void kernel_launch(void* const* d_in, const int* in_sizes, int n_in,
                              void* d_out, int out_size, void* d_ws, size_t ws_size,
                              hipStream_t stream) {
    const float* x        = (const float*)d_in[0];
    const float* patch_w  = (const float*)d_in[1];
    const float* patch_b  = (const float*)d_in[2];
    const float* pe_g     = (const float*)d_in[3];
    const float* pe_b     = (const float*)d_in[4];
    const float* blk_g    = (const float*)d_in[5];
    const float* blk_b    = (const float*)d_in[6];
    const float* cls_w    = (const float*)d_in[7];
    const float* cls_b    = (const float*)d_in[8];
    const float* f_in_w   = (const float*)d_in[9];
    const float* f_conv_w = (const float*)d_in[10];
    const float* f_conv_b = (const float*)d_in[11];
    const float* f_xp_w   = (const float*)d_in[12];
    const float* f_dt_w   = (const float*)d_in[13];
    const float* f_dt_b   = (const float*)d_in[14];
    const float* f_A_log  = (const float*)d_in[15];
    const float* f_D      = (const float*)d_in[16];
    const float* f_out_w  = (const float*)d_in[17];
    const float* b_in_w   = (const float*)d_in[18];
    const float* b_conv_w = (const float*)d_in[19];
    const float* b_conv_b = (const float*)d_in[20];
    const float* b_xp_w   = (const float*)d_in[21];
    const float* b_dt_w   = (const float*)d_in[22];
    const float* b_dt_b   = (const float*)d_in[23];
    const float* b_A_log  = (const float*)d_in[24];
    const float* b_D      = (const float*)d_in[25];
    const float* b_out_w  = (const float*)d_in[26];

    float* ws = (float*)d_ws;
    float* out = (float*)d_out;

    float* Hb        = ws + O_H;
    _Float16* H16    = (_Float16*)(ws + O_H16);
    float* XIf       = ws + O_XI_F;
    float* XIb       = ws + O_XI_B;
    float* Zf        = ws + O_Z_F;
    float* Zb        = ws + O_Z_B;
    _Float16* YsTf16 = (_Float16*)(ws + O_Z_F);   // after scan: tok-major ys f16
    _Float16* YsTb16 = (_Float16*)(ws + O_Z_B);
    float* XCf       = ws + O_XC_F;               // xcT_f; later head partials
    float* XCb       = ws + O_XC_B;
    float* DTRf      = ws + O_DTR_F;
    float* DTRb      = ws + O_DTR_B;
    float* BCf       = ws + O_BC_F;
    float* BCb       = ws + O_BC_B;
    _Float16* Xp16   = (_Float16*)(ws + O_YS_F);  // early
    float* TokRaw    = ws + O_YS_B;               // early
    _Float16* Y16f   = (_Float16*)(ws + O_YS_F);  // after scan
    _Float16* Y16b   = (_Float16*)(ws + O_YS_B);
    _Float16* PW16   = (_Float16*)(ws + O_PW16);
    _Float16* FIN16  = (_Float16*)(ws + O_FIN16);
    _Float16* BIN16  = (_Float16*)(ws + O_BIN16);
    _Float16* FOUT16 = (_Float16*)(ws + O_FOUT16);
    _Float16* BOUT16 = (_Float16*)(ws + O_BOUT16);

    // weight conversions
    cvt_f16<<<(192 * KP_PW + 255) / 256, 256, 0, stream>>>(patch_w, PW16, 192, 192, KP_PW);
    cvt_f16<<<(784 * KP_XZ + 255) / 256, 256, 0, stream>>>(f_in_w, FIN16, 784, DM, KP_XZ);
    cvt_f16<<<(784 * KP_XZ + 255) / 256, 256, 0, stream>>>(b_in_w, BIN16, 784, DM, KP_XZ);
    cvt_f16<<<(DM * KP_OP + 255) / 256, 256, 0, stream>>>(f_out_w, FOUT16, DM, DI, KP_OP);
    cvt_f16<<<(DM * KP_OP + 255) / 256, 256, 0, stream>>>(b_out_w, BOUT16, DM, DI, KP_OP);

    // patch embed
    gather_patch<<<(NTOK * 192) / 256, 256, 0, stream>>>(x, Xp16);
    mfma_gemm<<<dim3(NTOK / 128, 3), 256, 0, stream>>>(Xp16, PW16, patch_b, TokRaw,
                                                       192, KP_PW, 192, 0, 0);
    ln_silu_pos<<<NTOK / 4, 256, 0, stream>>>(TokRaw, pe_g, pe_b, Hb, H16);

    // xz projections -> chain-major fp32
    mfma_gemm<<<dim3(NTOK / 128, 7), 256, 0, stream>>>(H16, FIN16, nullptr, XIf,
                                                       DI, KP_XZ, 0, 1, 0);
    mfma_gemm<<<dim3(NTOK / 128, 7), 256, 0, stream>>>(H16, FIN16 + (size_t)DI * KP_XZ,
                                                       nullptr, Zf, DI, KP_XZ, 0, 1, 0);
    mfma_gemm<<<dim3(NTOK / 128, 7), 256, 0, stream>>>(H16, BIN16, nullptr, XIb,
                                                       DI, KP_XZ, 0, 1, 1);
    mfma_gemm<<<dim3(NTOK / 128, 7), 256, 0, stream>>>(H16, BIN16 + (size_t)DI * KP_XZ,
                                                       nullptr, Zb, DI, KP_XZ, 0, 1, 1);

    // conv + silu
    conv_silu_T<<<2 * CH, 256, 0, stream>>>(XIf, XIb, XCf, XCb,
                                            f_conv_w, f_conv_b, b_conv_w, b_conv_b);
    // x_dbl (fp32) -> dt + [B|C]
    gemm_xdbl<<<NTOK / 64, 256, 0, stream>>>(XCf, f_xp_w, DTRf, BCf);
    gemm_xdbl<<<NTOK / 64, 256, 0, stream>>>(XCb, b_xp_w, DTRb, BCb);
    // delta -> dlT (overwrites dead xiT)
    delta_kernel<<<(2 * (int)DI_SZ) / 256, 256, 0, stream>>>(
        DTRf, DTRb, XIf, XIb, f_dt_w, f_dt_b, b_dt_w, b_dt_b);
    // scan + gate -> y16 chain-major
    scan_kernel<<<2 * CH / 8, 256, 0, stream>>>(
        XIf, XIb, XCf, XCb, BCf, BCb, Zf, Zb, Y16f, Y16b,
        f_A_log, b_A_log, f_D, b_D);
    // transpose -> tok-major f16 (into dead Z regions)
    transp_y<<<dim3(16, 16, 14), 256, 0, stream>>>(Y16f, Y16b, YsTf16, YsTb16);
    // out projections -> fo/bo fp32 tok-major (into dead dlT regions)
    mfma_gemm<<<dim3(NTOK / 128, 4), 256, 0, stream>>>(YsTf16, FOUT16, nullptr, XIf,
                                                       DM, KP_OP, DM, 0, 0);
    mfma_gemm<<<dim3(NTOK / 128, 4), 256, 0, stream>>>(YsTb16, BOUT16, nullptr, XIb,
                                                       DM, KP_OP, DM, 0, 0);
    // head: partials (into dead XCf region) then reduce
    final_head<<<NTOK / 4, 256, 0, stream>>>(XIf, XIb, Hb, blk_g, blk_b, cls_w, XCf);
    head_reduce<<<B_, 256, 0, stream>>>(XCf, cls_b, out);
}

// Round 6
// 518.852 us; speedup vs baseline: 2.8162x; 1.1105x over previous
//
#include <hip/hip_runtime.h>
#include <cstdint>
#include <cstddef>

// ---------------- problem constants ----------------
constexpr int B_   = 16;
constexpr int L_   = 1024;
constexpr int E_   = 192;
constexpr int DM   = 196;   // D_MODEL
constexpr int DI   = 392;   // D_INNER
constexpr int DS   = 16;    // D_STATE
constexpr int DTR  = 13;    // DT_RANK
constexpr int NTOK = B_ * L_;            // 16384
constexpr int XDW  = DTR + 2 * DS;       // 45
constexpr int CH   = B_ * DI;            // 6272 chains per direction

constexpr int KP_XZ = 224;   // 196 padded to %32
constexpr int KP_OP = 416;   // 392 padded to %32
constexpr int KP_PW = 192;

constexpr size_t HW_SZ = (size_t)NTOK * DM;   // 3,211,264
constexpr size_t DI_SZ = (size_t)NTOK * DI;   // 6,422,528

// ---------------- workspace layout (float offsets, all 16B aligned) ----------------
constexpr size_t O_H     = 0;           // h fp32 (NTOK x 196)
constexpr size_t O_H16   = 3211264;     // h f16 (NTOK x 224)
constexpr size_t O_XI_F  = 5046272;     // xiT f32 -> dlT f32 -> fo f32
constexpr size_t O_XI_B  = 11468800;
constexpr size_t O_Z_F   = 17891328;    // zT f32; later ysT16 tok-major f16
constexpr size_t O_Z_B   = 24313856;
constexpr size_t O_XC_F  = 30736384;    // xcT f32; later head partials
constexpr size_t O_XC_B  = 37158912;
constexpr size_t O_DTR_F = 43581440;    // dt f32 (NTOK x 13)
constexpr size_t O_DTR_B = 43794432;
constexpr size_t O_BC_F  = 44007424;    // [B|C] f32 (NTOK x 32)
constexpr size_t O_BC_B  = 44531712;
constexpr size_t O_YS_F  = 45056000;    // early Xp f16; later y16 chain-major
constexpr size_t O_YS_B  = 48267264;    // early tok_raw f32; later y16
constexpr size_t O_PW16  = 51478528;    // patch_w f16 192x192 (36864 f16)
constexpr size_t O_FIN16 = 51496960;    // f_in_w f16 784x224
constexpr size_t O_BIN16 = 51584768;
constexpr size_t O_FOUT16= 51672576;    // f_out_w f16 196x416
constexpr size_t O_BOUT16= 51713344;    // end 51,754,112 (~198 MiB)

typedef _Float16 half8 __attribute__((ext_vector_type(8)));
typedef float f32x4v __attribute__((ext_vector_type(4)));

// ---------------- helpers ----------------
__device__ __forceinline__ float siluf(float x) {
    return x / (1.f + __expf(-x));
}

__device__ __forceinline__ float blk_sum(float v, float* red) {
    #pragma unroll
    for (int o = 32; o > 0; o >>= 1) v += __shfl_down(v, o);
    int w = threadIdx.x >> 6;
    __syncthreads();
    if ((threadIdx.x & 63) == 0) red[w] = v;
    __syncthreads();
    return red[0] + red[1] + red[2] + red[3];
}

// ---------------- cvt all 5 weight tensors in one launch ----------------
// dst regions are contiguous f16 starting at O_PW16.
__global__ __launch_bounds__(256) void cvt_all(const float* __restrict__ pw,
                                               const float* __restrict__ fin,
                                               const float* __restrict__ bin,
                                               const float* __restrict__ fout,
                                               const float* __restrict__ bout,
                                               _Float16* __restrict__ dst) {
    int i = blockIdx.x * 256 + threadIdx.x;       // < 551168
    const float* src; int K, Kp, off;
    if (i < 36864)       { src = pw;   K = 192; Kp = 192; off = i; }
    else if (i < 212480) { src = fin;  K = 196; Kp = 224; off = i - 36864; }
    else if (i < 388096) { src = bin;  K = 196; Kp = 224; off = i - 212480; }
    else if (i < 469632) { src = fout; K = 392; Kp = 416; off = i - 388096; }
    else                 { src = bout; K = 392; Kp = 416; off = i - 469632; }
    int n = off / Kp, k = off - n * Kp;
    dst[i] = (_Float16)(k < K ? src[(size_t)n * K + k] : 0.f);
}

// ---------------- K0: gather patches into (NTOK, 192) f16 ----------------
__global__ __launch_bounds__(256) void gather_patch(const float* __restrict__ x,
                                                    _Float16* __restrict__ Xp) {
    int i = blockIdx.x * 256 + threadIdx.x;
    int tok = i / 192, r = i - tok * 192;
    int c = r >> 6, pq = r & 63, p = pq >> 3, q = pq & 7;
    int b = tok >> 10, l = tok & 1023, hh = l >> 5, wv = l & 31;
    Xp[i] = (_Float16)x[(((size_t)(b * 3 + c) * 256 + hh * 8 + p) << 8) + wv * 8 + q];
}

// ---------------- shared MFMA GEMM core ----------------
// block 256 = 4 waves; tile 128(m) x 64(n); A tok-major f16; optional per-1024 flip.
template <int MODE>   // 0: tok-major store (+bias); 1: chain-major store
__device__ __forceinline__ void mfma_core(const _Float16* __restrict__ A,
                                          const _Float16* __restrict__ W,
                                          const float* __restrict__ bias,
                                          float* __restrict__ C,
                                          int N, int Kpad, int ldc,
                                          int flip, int m_blk, int n_blk) {
    const int tid = threadIdx.x;
    const int wv = tid >> 6, lane = tid & 63;
    const int col = lane & 15, quad = lane >> 4;
    const int m_base = m_blk * 128 + wv * 32;
    const int n_base = n_blk * 64;

    int r0 = m_base + col, r1 = m_base + 16 + col;
    if (flip) {
        r0 = (r0 & ~1023) + (1023 - (r0 & 1023));
        r1 = (r1 & ~1023) + (1023 - (r1 & 1023));
    }
    const _Float16* a0p = A + (size_t)r0 * Kpad + quad * 8;
    const _Float16* a1p = A + (size_t)r1 * Kpad + quad * 8;

    const _Float16* bp[4];
    bool bok[4];
    #pragma unroll
    for (int j = 0; j < 4; ++j) {
        int n = n_base + j * 16 + col;
        bok[j] = (n < N);
        bp[j] = W + (size_t)(bok[j] ? n : 0) * Kpad + quad * 8;
    }

    f32x4v acc[2][4];
    #pragma unroll
    for (int i = 0; i < 2; ++i)
        #pragma unroll
        for (int j = 0; j < 4; ++j)
            #pragma unroll
            for (int r = 0; r < 4; ++r) acc[i][j][r] = 0.f;

    half8 bzero;
    #pragma unroll
    for (int q = 0; q < 8; ++q) bzero[q] = (_Float16)0.f;

    for (int k0 = 0; k0 < Kpad; k0 += 32) {
        half8 a0 = *(const half8*)(a0p + k0);
        half8 a1 = *(const half8*)(a1p + k0);
        #pragma unroll
        for (int j = 0; j < 4; ++j) {
            half8 bv = bzero;
            if (bok[j]) bv = *(const half8*)(bp[j] + k0);
            acc[0][j] = __builtin_amdgcn_mfma_f32_16x16x32_f16(a0, bv, acc[0][j], 0, 0, 0);
            acc[1][j] = __builtin_amdgcn_mfma_f32_16x16x32_f16(a1, bv, acc[1][j], 0, 0, 0);
        }
    }

    if (MODE == 0) {
        #pragma unroll
        for (int i = 0; i < 2; ++i) {
            int mrow = m_base + i * 16 + quad * 4;
            #pragma unroll
            for (int j = 0; j < 4; ++j) {
                int n = n_base + j * 16 + col;
                if (n < N) {
                    float bv = bias ? bias[n] : 0.f;
                    #pragma unroll
                    for (int r = 0; r < 4; ++r)
                        C[(size_t)(mrow + r) * ldc + n] = acc[i][j][r] + bv;
                }
            }
        }
    } else {
        const int bb = m_base >> 10;
        const int t0 = m_base & 1023;
        #pragma unroll
        for (int i = 0; i < 2; ++i) {
            int tt = t0 + i * 16 + quad * 4;
            #pragma unroll
            for (int j = 0; j < 4; ++j) {
                int n = n_base + j * 16 + col;
                if (n < N) {
                    float4 v = {acc[i][j][0], acc[i][j][1], acc[i][j][2], acc[i][j][3]};
                    *(float4*)(C + (((size_t)(bb * N + n)) << 10) + tt) = v;
                }
            }
        }
    }
}

// patch embed GEMM (tok-major, bias)
__global__ __launch_bounds__(256) void mfma_patch(const _Float16* __restrict__ A,
                                                  const _Float16* __restrict__ W,
                                                  const float* __restrict__ bias,
                                                  float* __restrict__ C) {
    mfma_core<0>(A, W, bias, C, 192, KP_PW, 192, 0, blockIdx.x, blockIdx.y);
}

// merged xz projections: z = {f_xi, f_z, b_xi, b_z}
__global__ __launch_bounds__(256) void mfma_xz(const _Float16* __restrict__ A,
                                               const _Float16* __restrict__ Wf,
                                               const _Float16* __restrict__ Wb,
                                               float* __restrict__ C0, float* __restrict__ C1,
                                               float* __restrict__ C2, float* __restrict__ C3) {
    const int zi = blockIdx.z;
    const _Float16* W = (zi < 2 ? Wf : Wb) + (size_t)(zi & 1) * DI * KP_XZ;
    float* C = (zi == 0) ? C0 : (zi == 1) ? C1 : (zi == 2) ? C2 : C3;
    mfma_core<1>(A, W, nullptr, C, DI, KP_XZ, 0, zi >> 1, blockIdx.x, blockIdx.y);
}

// merged out-projections: z = {fwd, bwd}
__global__ __launch_bounds__(256) void mfma_op(const _Float16* __restrict__ Af,
                                               const _Float16* __restrict__ Ab,
                                               const _Float16* __restrict__ Wf,
                                               const _Float16* __restrict__ Wb,
                                               float* __restrict__ Cf, float* __restrict__ Cb) {
    const int zi = blockIdx.z;
    mfma_core<0>(zi ? Ab : Af, zi ? Wb : Wf, nullptr, zi ? Cb : Cf,
                 DM, KP_OP, DM, 0, blockIdx.x, blockIdx.y);
}

// ---------------- K1b: LN + SiLU + pos -> h fp32 + h f16; one wave per token ----------------
__global__ __launch_bounds__(256) void ln_silu_pos(const float* __restrict__ tok,
                                                   const float* __restrict__ g,
                                                   const float* __restrict__ bb,
                                                   float* __restrict__ h,
                                                   _Float16* __restrict__ h16) {
    const int w = threadIdx.x >> 6, lane = threadIdx.x & 63;
    const int t = blockIdx.x * 4 + w;
    const float* tp = tok + (size_t)t * E_;
    float v[3];
    float s1 = 0.f, s2 = 0.f;
    #pragma unroll
    for (int i = 0; i < 3; ++i) {
        v[i] = tp[lane + i * 64];
        s1 += v[i];
        s2 = fmaf(v[i], v[i], s2);
    }
    #pragma unroll
    for (int o = 32; o > 0; o >>= 1) {
        s1 += __shfl_xor(s1, o);
        s2 += __shfl_xor(s2, o);
    }
    float mean = s1 * (1.f / E_);
    float var = s2 * (1.f / E_) - mean * mean;
    float inv = rsqrtf(var + 1e-5f);
    float* hp = h + (size_t)t * DM;
    _Float16* hq = h16 + (size_t)t * KP_XZ;
    #pragma unroll
    for (int i = 0; i < 3; ++i) {
        int e = lane + i * 64;
        float o = siluf((v[i] - mean) * inv * g[e] + bb[e]);
        hp[e] = o;
        hq[e] = (_Float16)o;
    }
    const int l = t & 1023;
    const float scale = 0.19634954084936207f;  // 2*pi/32
    if (lane < 4) {
        float pv = (lane == 0) ? sinf(l * scale)
                 : (lane == 1) ? cosf(l * scale)
                 : (lane == 2) ? sinf((float)(l >> 5) * scale)
                 :               cosf((float)(l >> 5) * scale);
        hp[E_ + lane] = pv;
        hq[E_ + lane] = (_Float16)pv;
    } else if (lane < 32) {
        hq[192 + lane] = (_Float16)0.f;   // pad 196..223
    }
}

// ---------------- K3: depthwise causal conv(4)+SiLU chain-major ----------------
__global__ __launch_bounds__(256) void conv_silu_T(
        const float* __restrict__ xiT_f, const float* __restrict__ xiT_b,
        float* __restrict__ xcT_f, float* __restrict__ xcT_b,
        const float* __restrict__ fw, const float* __restrict__ fb,
        const float* __restrict__ bw, const float* __restrict__ bb2) {
    int i = blockIdx.x * 256 + threadIdx.x;        // < 2*CH*256
    int rall = i >> 8;
    int dir = rall >= CH;
    int r = rall - (dir ? CH : 0);
    int d = r % DI;
    int t0 = (i & 255) << 2;
    const float* xi = (dir ? xiT_b : xiT_f) + ((size_t)r << 10) + t0;
    float cur[4], prev[4] = {0.f, 0.f, 0.f, 0.f};
    *(float4*)cur = *(const float4*)xi;
    if (t0) *(float4*)prev = *(const float4*)(xi - 4);
    const float* w = (dir ? bw : fw) + d * 4;
    float bias = (dir ? bb2 : fb)[d];
    float xv[7] = {prev[1], prev[2], prev[3], cur[0], cur[1], cur[2], cur[3]};
    float o[4];
    #pragma unroll
    for (int tt = 0; tt < 4; ++tt) {
        float a = bias;
        #pragma unroll
        for (int k = 0; k < 4; ++k) a = fmaf(xv[tt + k], w[k], a);
        o[tt] = siluf(a);
    }
    *(float4*)((dir ? xcT_b : xcT_f) + ((size_t)r << 10) + t0) = *(float4*)o;
}

// ---------------- K2b: x_dbl GEMM (fp32), both dirs in grid.y ----------------
__global__ __launch_bounds__(256) void gemm_xdbl(const float* __restrict__ Af,
                                                 const float* __restrict__ Ab,
                                                 const float* __restrict__ Wf,
                                                 const float* __restrict__ Wb,
                                                 float* __restrict__ dtrf,
                                                 float* __restrict__ dtrb,
                                                 float* __restrict__ bcf,
                                                 float* __restrict__ bcb) {
    const int yi = blockIdx.y;
    const float* A = yi ? Ab : Af;
    const float* W = yi ? Wb : Wf;
    float* dtr = yi ? dtrb : dtrf;
    float* bc = yi ? bcb : bcf;
    __shared__ __align__(16) float As[16][68];
    __shared__ __align__(16) float Ws[16][68];
    const int m0 = blockIdx.x * 64;
    const int t = threadIdx.x;
    const int tx = t & 15, ty = t >> 4;
    float acc[4][4] = {};
    const int arow_l = t >> 2;
    const int kq = (t & 3) * 4;
    const int bb_ = m0 >> 10, tt0 = m0 & 1023;
    for (int kt = 0; kt < 25; ++kt) {              // K=392: 24*16+8
        const int k0 = kt << 4;
        {
            int kr = t >> 4, tc = t & 15;
            int kk = k0 + kr;
            float4 v = {0.f, 0.f, 0.f, 0.f};
            if (kk < DI)
                v = *(const float4*)(A + (((size_t)bb_ * DI + kk) << 10) + tt0 + tc * 4);
            *(float4*)&As[kr][tc * 4] = v;
        }
        {
            bool okn = arow_l < XDW;
            const float* wp = W + (size_t)arow_l * DI;
            #pragma unroll
            for (int jj = 0; jj < 4; ++jj) {
                int kk = k0 + kq + jj;
                Ws[kq + jj][arow_l] = (okn && kk < DI) ? wp[kk] : 0.f;
            }
        }
        __syncthreads();
        #pragma unroll
        for (int k = 0; k < 16; ++k) {
            float av[4], wv[4];
            *(float4*)av = *(const float4*)&As[k][ty * 4];
            *(float4*)wv = *(const float4*)&Ws[k][tx * 4];
            #pragma unroll
            for (int i = 0; i < 4; ++i)
                #pragma unroll
                for (int j = 0; j < 4; ++j)
                    acc[i][j] = fmaf(av[i], wv[j], acc[i][j]);
        }
        __syncthreads();
    }
    #pragma unroll
    for (int i = 0; i < 4; ++i) {
        int m = m0 + ty * 4 + i;
        #pragma unroll
        for (int j = 0; j < 4; ++j) {
            int n = tx * 4 + j;
            float v = acc[i][j];
            if (n < DTR) dtr[(size_t)m * DTR + n] = v;
            else if (n < XDW) bc[(size_t)m * 32 + (n - DTR)] = v;
        }
    }
}

// ---------------- K4: delta = softplus(dt @ dt_w^T + dt_b) -> chain-major ----------------
__global__ __launch_bounds__(256) void delta_kernel(
        const float* __restrict__ dtr_f, const float* __restrict__ dtr_b,
        float* __restrict__ dlT_f, float* __restrict__ dlT_b,
        const float* __restrict__ f_dt_w, const float* __restrict__ f_dt_b,
        const float* __restrict__ b_dt_w, const float* __restrict__ b_dt_b) {
    int i = blockIdx.x * 256 + threadIdx.x;       // < 2*DI_SZ
    int dir = i >= (int)DI_SZ;
    int j = dir ? i - (int)DI_SZ : i;             // r*1024 + t
    int r = j >> 10, t = j & 1023;
    int b = r / DI, d = r - (r / DI) * DI;
    size_t tok = ((size_t)b << 10) + t;
    const float* xd = (dir ? dtr_b : dtr_f) + tok * DTR;
    const float* w = (dir ? b_dt_w : f_dt_w) + d * DTR;
    float acc = (dir ? b_dt_b : f_dt_b)[d];
    #pragma unroll
    for (int q = 0; q < DTR; ++q) acc = fmaf(xd[q], w[q], acc);
    float sp = fmaxf(acc, 0.f) + log1pf(__expf(-fabsf(acc)));
    (dir ? dlT_b : dlT_f)[j] = sp;
}

// ---------------- K5: chunked scan, 4 lanes/chain x 4 states, fused gate ----------------
// f16 output written as coalesced half8 per lane (lane ni owns t-window ni*8 per 32-t block)
__global__ __launch_bounds__(256) void scan_kernel(
        const float* __restrict__ dlT_f, const float* __restrict__ dlT_b,
        const float* __restrict__ xcT_f, const float* __restrict__ xcT_b,
        const float* __restrict__ bc_f,  const float* __restrict__ bc_b,
        const float* __restrict__ zT_f,  const float* __restrict__ zT_b,
        _Float16* __restrict__ y16_f,    _Float16* __restrict__ y16_b,
        const float* __restrict__ fA, const float* __restrict__ bA,
        const float* __restrict__ fD, const float* __restrict__ bD) {
    __shared__ float sP[8][8][16];
    __shared__ float sH[8][8][16];
    __shared__ float sI[8][8][16];
    const int tid = threadIdx.x;
    const int ni = tid & 3;
    const int c  = (tid >> 2) & 7;
    const int ch_l = tid >> 5;
    const int chain = blockIdx.x * 8 + ch_l;
    const int dir = chain >= CH;
    const int r = chain - (dir ? CH : 0);
    const int b = r / DI, d = r - (r / DI) * DI;

    const float* dlT = (dir ? dlT_b : dlT_f) + ((size_t)r << 10);
    const float* uT  = (dir ? xcT_b : xcT_f) + ((size_t)r << 10);
    const float* zT  = (dir ? zT_b  : zT_f)  + ((size_t)r << 10);
    const float* BC  = (dir ? bc_b  : bc_f)  + (((size_t)b << 10) * 32);
    _Float16* y16    = (dir ? y16_b : y16_f) + ((size_t)r << 10);
    const float* Al  = (dir ? bA : fA) + d * DS + ni * 4;
    float Av[4];
    #pragma unroll
    for (int i = 0; i < 4; ++i) Av[i] = -__expf(Al[i]);
    const float Dd = (dir ? bD : fD)[d];
    const int t0 = c << 7;

    // ---- phase A ----
    if (c < 7) {
        float h[4] = {0.f, 0.f, 0.f, 0.f};
        float S = 0.f;
        for (int g = 0; g < 32; ++g) {
            const int tg = t0 + g * 4;
            float4 d4 = *(const float4*)(dlT + tg);
            float4 u4 = *(const float4*)(uT + tg);
            float dv[4] = {d4.x, d4.y, d4.z, d4.w};
            float uv[4] = {u4.x, u4.y, u4.z, u4.w};
            #pragma unroll
            for (int tt = 0; tt < 4; ++tt) {
                float4 B4 = *(const float4*)(BC + (size_t)(tg + tt) * 32 + ni * 4);
                float w = dv[tt] * uv[tt];
                S += dv[tt];
                float Bv[4] = {B4.x, B4.y, B4.z, B4.w};
                #pragma unroll
                for (int i = 0; i < 4; ++i)
                    h[i] = fmaf(__expf(dv[tt] * Av[i]), h[i], w * Bv[i]);
            }
        }
        #pragma unroll
        for (int i = 0; i < 4; ++i) {
            sP[ch_l][c][ni * 4 + i] = __expf(S * Av[i]);
            sH[ch_l][c][ni * 4 + i] = h[i];
        }
    }
    __syncthreads();

    // ---- phase B ----
    if (tid < 128) {
        const int ch = tid >> 4, n = tid & 15;
        float hi = 0.f;
        #pragma unroll
        for (int cc = 0; cc < 8; ++cc) {
            sI[ch][cc][n] = hi;
            if (cc < 7) hi = sH[ch][cc][n] + sP[ch][cc][n] * hi;
        }
    }
    __syncthreads();

    // ---- phase C ----
    {
        float h[4];
        #pragma unroll
        for (int i = 0; i < 4; ++i) h[i] = sI[ch_l][c][ni * 4 + i];
        _Float16 ybuf[8] __attribute__((aligned(16)));
        for (int g = 0; g < 32; ++g) {
            const int tg = t0 + g * 4;
            float4 d4 = *(const float4*)(dlT + tg);
            float4 u4 = *(const float4*)(uT + tg);
            float4 z4 = *(const float4*)(zT + tg);
            float dv[4] = {d4.x, d4.y, d4.z, d4.w};
            float uv[4] = {u4.x, u4.y, u4.z, u4.w};
            float zv[4] = {z4.x, z4.y, z4.z, z4.w};
            float pq[4];
            #pragma unroll
            for (int tt = 0; tt < 4; ++tt) {
                float4 B4 = *(const float4*)(BC + (size_t)(tg + tt) * 32 + ni * 4);
                float4 C4 = *(const float4*)(BC + (size_t)(tg + tt) * 32 + 16 + ni * 4);
                float w = dv[tt] * uv[tt];
                float Bv[4] = {B4.x, B4.y, B4.z, B4.w};
                float Cv[4] = {C4.x, C4.y, C4.z, C4.w};
                float p = 0.f;
                #pragma unroll
                for (int i = 0; i < 4; ++i) {
                    h[i] = fmaf(__expf(dv[tt] * Av[i]), h[i], w * Bv[i]);
                    p = fmaf(h[i], Cv[i], p);
                }
                pq[tt] = p;
            }
            #pragma unroll
            for (int tt = 0; tt < 4; ++tt) {
                pq[tt] += __shfl_xor(pq[tt], 1);
                pq[tt] += __shfl_xor(pq[tt], 2);
            }
            // all 4 lanes now hold the full sums; lane ni packs its own window
            if (((g >> 1) & 3) == ni) {
                const int base = (g & 1) * 4;
                #pragma unroll
                for (int tt = 0; tt < 4; ++tt)
                    ybuf[base + tt] =
                        (_Float16)((pq[tt] + Dd * uv[tt]) * siluf(zv[tt]));
            }
            if ((g & 7) == 7)
                *(half8*)(y16 + t0 + ((g >> 3) << 5) + ni * 8) = *(half8*)ybuf;
        }
    }
}

// ---------------- K5b: transpose y16 chain-major -> tok-major f16 padded 416 ----------------
__global__ __launch_bounds__(256) void transp_y(
        const _Float16* __restrict__ yf, const _Float16* __restrict__ yb,
        _Float16* __restrict__ of, _Float16* __restrict__ ob) {
    __shared__ _Float16 tile[64][72];
    const int dblk = blockIdx.z % 7, dir = blockIdx.z / 7;
    const int b = blockIdx.y, tb = blockIdx.x;
    const _Float16* y = dir ? yb : yf;
    _Float16* o = dir ? ob : of;
    const int d0 = dblk * 64, t0 = tb * 64;
    const int dl = threadIdx.x >> 2, ts = (threadIdx.x & 3) * 16;
    const int d = d0 + dl;
    if (d < DI) {
        const _Float16* src = y + (((size_t)(b * DI + d)) << 10) + t0 + ts;
        *(half8*)&tile[dl][ts] = *(const half8*)src;
        *(half8*)&tile[dl][ts + 8] = *(const half8*)(src + 8);
    } else {
        #pragma unroll
        for (int q = 0; q < 16; ++q) tile[dl][ts + q] = (_Float16)0.f;
    }
    __syncthreads();
    const int tl = threadIdx.x >> 2, ds = (threadIdx.x & 3) * 16;
    if (d0 + ds < KP_OP) {
        _Float16 v[16] __attribute__((aligned(16)));
        #pragma unroll
        for (int q = 0; q < 16; ++q) v[q] = tile[ds + q][tl];
        _Float16* dst = o + ((size_t)((b << 10) + t0 + tl)) * KP_OP + d0 + ds;
        *(half8*)dst = *(half8*)&v[0];
        *(half8*)(dst + 8) = *(half8*)&v[8];
    }
}

// ---------------- K8a: head partials — one wave per token, no atomics ----------------
__global__ __launch_bounds__(256) void final_head(
        const float* __restrict__ fo, const float* __restrict__ bo,
        const float* __restrict__ h, const float* __restrict__ g,
        const float* __restrict__ bb, const float* __restrict__ cls_w,
        float* __restrict__ partial) {
    const int w = threadIdx.x >> 6, lane = threadIdx.x & 63;
    const int t = blockIdx.x * 4 + w;
    const int b = t >> 10, l = t & 1023;
    const float* fp = fo + (size_t)t * DM;
    const float* bp = bo + ((size_t)(b << 10) + (1023 - l)) * DM;
    const float* hp = h + (size_t)t * DM;
    float v[4];
    float s1 = 0.f, s2 = 0.f;
    #pragma unroll
    for (int i = 0; i < 4; ++i) {
        int e = lane + i * 64;
        bool ok = (i < 3) || (lane < 4);
        float vv = ok ? 0.5f * (fp[e] + bp[e]) : 0.f;
        v[i] = vv;
        s1 += vv;
        s2 = fmaf(vv, vv, s2);
    }
    #pragma unroll
    for (int o = 32; o > 0; o >>= 1) {
        s1 += __shfl_xor(s1, o);
        s2 += __shfl_xor(s2, o);
    }
    float mean = s1 * (1.f / DM);
    float var = s2 * (1.f / DM) - mean * mean;
    float inv = rsqrtf(var + 1e-5f);
    float c = 0.f;
    #pragma unroll
    for (int i = 0; i < 4; ++i) {
        int e = lane + i * 64;
        bool ok = (i < 3) || (lane < 4);
        if (ok) {
            float o2 = (v[i] - mean) * inv * g[e] + bb[e];
            o2 = siluf(o2) + hp[e];
            c = fmaf(o2, cls_w[e], c);
        }
    }
    #pragma unroll
    for (int o = 32; o > 0; o >>= 1) c += __shfl_xor(c, o);
    if (lane == 0) partial[t] = c;
}

// ---------------- K8b: reduce 1024 partials per batch -> out ----------------
__global__ __launch_bounds__(256) void head_reduce(const float* __restrict__ partial,
                                                   const float* __restrict__ cls_b,
                                                   float* __restrict__ out) {
    __shared__ float red[4];
    const int b = blockIdx.x;
    const float* p = partial + ((size_t)b << 10);
    float s = 0.f;
    for (int i = threadIdx.x; i < 1024; i += 256) s += p[i];
    s = blk_sum(s, red);
    if (threadIdx.x == 0) out[b] = s * (1.f / 1024.f) + cls_b[0];
}

// ---------------- launch ----------------
extern "C" void kernel_launch(void* const* d_in, const int* in_sizes, int n_in,
                              void* d_out, int out_size, void* d_ws, size_t ws_size,
                              hipStream_t stream) {
    const float* x        = (const float*)d_in[0];
    const float* patch_w  = (const float*)d_in[1];
    const float* patch_b  = (const float*)d_in[2];
    const float* pe_g     = (const float*)d_in[3];
    const float* pe_b     = (const float*)d_in[4];
    const float* blk_g    = (const float*)d_in[5];
    const float* blk_b    = (const float*)d_in[6];
    const float* cls_w    = (const float*)d_in[7];
    const float* cls_b    = (const float*)d_in[8];
    const float* f_in_w   = (const float*)d_in[9];
    const float* f_conv_w = (const float*)d_in[10];
    const float* f_conv_b = (const float*)d_in[11];
    const float* f_xp_w   = (const float*)d_in[12];
    const float* f_dt_w   = (const float*)d_in[13];
    const float* f_dt_b   = (const float*)d_in[14];
    const float* f_A_log  = (const float*)d_in[15];
    const float* f_D      = (const float*)d_in[16];
    const float* f_out_w  = (const float*)d_in[17];
    const float* b_in_w   = (const float*)d_in[18];
    const float* b_conv_w = (const float*)d_in[19];
    const float* b_conv_b = (const float*)d_in[20];
    const float* b_xp_w   = (const float*)d_in[21];
    const float* b_dt_w   = (const float*)d_in[22];
    const float* b_dt_b   = (const float*)d_in[23];
    const float* b_A_log  = (const float*)d_in[24];
    const float* b_D      = (const float*)d_in[25];
    const float* b_out_w  = (const float*)d_in[26];

    float* ws = (float*)d_ws;
    float* out = (float*)d_out;

    float* Hb        = ws + O_H;
    _Float16* H16    = (_Float16*)(ws + O_H16);
    float* XIf       = ws + O_XI_F;
    float* XIb       = ws + O_XI_B;
    float* Zf        = ws + O_Z_F;
    float* Zb        = ws + O_Z_B;
    _Float16* YsTf16 = (_Float16*)(ws + O_Z_F);   // after scan: tok-major ys f16
    _Float16* YsTb16 = (_Float16*)(ws + O_Z_B);
    float* XCf       = ws + O_XC_F;               // xcT_f; later head partials
    float* XCb       = ws + O_XC_B;
    float* DTRf      = ws + O_DTR_F;
    float* DTRb      = ws + O_DTR_B;
    float* BCf       = ws + O_BC_F;
    float* BCb       = ws + O_BC_B;
    _Float16* Xp16   = (_Float16*)(ws + O_YS_F);  // early
    float* TokRaw    = ws + O_YS_B;               // early
    _Float16* Y16f   = (_Float16*)(ws + O_YS_F);  // after scan
    _Float16* Y16b   = (_Float16*)(ws + O_YS_B);
    _Float16* PW16   = (_Float16*)(ws + O_PW16);
    _Float16* FIN16  = (_Float16*)(ws + O_FIN16);
    _Float16* BIN16  = (_Float16*)(ws + O_BIN16);
    _Float16* FOUT16 = (_Float16*)(ws + O_FOUT16);
    _Float16* BOUT16 = (_Float16*)(ws + O_BOUT16);

    // weight conversions (single launch, dst regions contiguous from PW16)
    cvt_all<<<2153, 256, 0, stream>>>(patch_w, f_in_w, b_in_w, f_out_w, b_out_w, PW16);

    // patch embed
    gather_patch<<<(NTOK * 192) / 256, 256, 0, stream>>>(x, Xp16);
    mfma_patch<<<dim3(NTOK / 128, 3), 256, 0, stream>>>(Xp16, PW16, patch_b, TokRaw);
    ln_silu_pos<<<NTOK / 4, 256, 0, stream>>>(TokRaw, pe_g, pe_b, Hb, H16);

    // xz projections -> chain-major fp32 (merged: z = f_xi, f_z, b_xi, b_z)
    mfma_xz<<<dim3(NTOK / 128, 7, 4), 256, 0, stream>>>(H16, FIN16, BIN16,
                                                        XIf, Zf, XIb, Zb);
    // conv + silu
    conv_silu_T<<<2 * CH, 256, 0, stream>>>(XIf, XIb, XCf, XCb,
                                            f_conv_w, f_conv_b, b_conv_w, b_conv_b);
    // x_dbl (fp32) -> dt + [B|C] (merged dirs)
    gemm_xdbl<<<dim3(NTOK / 64, 2), 256, 0, stream>>>(XCf, XCb, f_xp_w, b_xp_w,
                                                      DTRf, DTRb, BCf, BCb);
    // delta -> dlT (overwrites dead xiT)
    delta_kernel<<<(2 * (int)DI_SZ) / 256, 256, 0, stream>>>(
        DTRf, DTRb, XIf, XIb, f_dt_w, f_dt_b, b_dt_w, b_dt_b);
    // scan + gate -> y16 chain-major (coalesced half8 stores)
    scan_kernel<<<2 * CH / 8, 256, 0, stream>>>(
        XIf, XIb, XCf, XCb, BCf, BCb, Zf, Zb, Y16f, Y16b,
        f_A_log, b_A_log, f_D, b_D);
    // transpose -> tok-major f16 (into dead Z regions)
    transp_y<<<dim3(16, 16, 14), 256, 0, stream>>>(Y16f, Y16b, YsTf16, YsTb16);
    // out projections -> fo/bo fp32 tok-major (merged dirs)
    mfma_op<<<dim3(NTOK / 128, 4, 2), 256, 0, stream>>>(YsTf16, YsTb16,
                                                        FOUT16, BOUT16, XIf, XIb);
    // head: partials (into dead XCf region) then reduce
    final_head<<<NTOK / 4, 256, 0, stream>>>(XIf, XIb, Hb, blk_g, blk_b, cls_w, XCf);
    head_reduce<<<B_, 256, 0, stream>>>(XCf, cls_b, out);
}